// Round 16
// baseline (525.208 us; speedup 1.0000x reference)
//
#include <hip/hip_runtime.h>
#include <hip/hip_bf16.h>
#include <hip/hip_fp16.h>

static constexpr int NF   = 50;   // input features
static constexpr int C1   = 64;   // conv1/conv2 channels
static constexpr int OUTF = 16;   // final output features
static constexpr int SCAN_T = 256;
static constexpr int SCAN_I = 4;
static constexpr float DEG_SCALE   = 8388608.f;      // 2^23 fixed-point for packed deg
static constexpr float DEG_INV     = 1.f / 8388608.f;

// ---------------------------------------------------------------- CSR build
// ONE packed 64-bit atomic per edge: high word = edge count, low word = fixed-point
// weighted degree. Returned old high word = this edge's rank within its row.
__global__ void pass1_kernel(const int* __restrict__ row, const float* __restrict__ w,
                             unsigned long long* __restrict__ pcd, int* __restrict__ rank, int e)
{
    int i = blockIdx.x * blockDim.x + threadIdx.x;
    if (i < e) {
        int r = row[i];
        unsigned int wq = (unsigned int)(w[i] * DEG_SCALE + 0.5f);
        unsigned long long pk = (1ULL << 32) | (unsigned long long)wq;
        unsigned long long old = atomicAdd(&pcd[r], pk);
        rank[i] = (int)(old >> 32);
    }
}

__global__ void dis_kernel(const unsigned long long* __restrict__ pcd,
                           float* __restrict__ dis, int* __restrict__ cnt, int n)
{
    int i = blockIdx.x * blockDim.x + threadIdx.x;
    if (i < n) {
        unsigned long long pk = pcd[i];
        int c = (int)(pk >> 32);
        float d = (float)(unsigned int)(pk & 0xFFFFFFFFu) * DEG_INV;
        cnt[i] = c;
        dis[i] = (d > 0.f) ? (1.f / sqrtf(d)) : 0.f;
    }
}

__global__ void scan_partial(const int* __restrict__ cnt, int* __restrict__ bsum, int n)
{
    __shared__ int sm[SCAN_T];
    int t = threadIdx.x;
    int base = blockIdx.x * SCAN_T * SCAN_I + t * SCAN_I;
    int s = 0;
    #pragma unroll
    for (int k = 0; k < SCAN_I; ++k) { int i = base + k; if (i < n) s += cnt[i]; }
    sm[t] = s; __syncthreads();
    for (int off = SCAN_T / 2; off > 0; off >>= 1) {
        if (t < off) sm[t] += sm[t + off];
        __syncthreads();
    }
    if (t == 0) bsum[blockIdx.x] = sm[0];
}

// single block; requires nb <= 256 (here nb = 98)
__global__ void scan_bsums(int* __restrict__ bsum, int nb)
{
    __shared__ int sm[256];
    int t = threadIdx.x;
    sm[t] = (t < nb) ? bsum[t] : 0;
    __syncthreads();
    for (int off = 1; off < 256; off <<= 1) {
        int v = (t >= off) ? sm[t - off] : 0;
        __syncthreads();
        sm[t] += v;
        __syncthreads();
    }
    if (t < nb) bsum[t] = (t == 0) ? 0 : sm[t - 1];   // exclusive
}

__global__ void scan_final(const int* __restrict__ cnt, const int* __restrict__ bsum,
                           int* __restrict__ rowptr, int n)
{
    __shared__ int sm[SCAN_T];
    int t = threadIdx.x;
    int base = blockIdx.x * SCAN_T * SCAN_I + t * SCAN_I;
    int v[SCAN_I]; int s = 0;
    #pragma unroll
    for (int k = 0; k < SCAN_I; ++k) { int i = base + k; v[k] = (i < n) ? cnt[i] : 0; s += v[k]; }
    sm[t] = s; __syncthreads();
    for (int off = 1; off < SCAN_T; off <<= 1) {
        int x = (t >= off) ? sm[t - off] : 0;
        __syncthreads();
        sm[t] += x;
        __syncthreads();
    }
    int pref = bsum[blockIdx.x] + sm[t] - s;   // thread-exclusive prefix
    #pragma unroll
    for (int k = 0; k < SCAN_I; ++k) {
        int i = base + k;
        if (i < n) { rowptr[i] = pref; pref += v[k]; }
    }
}

// atomic-free scatter: pos = rowptr[row] + rank. Writes interleaved (col, norm) int2.
__global__ void scatter_kernel(const int* __restrict__ row, const int* __restrict__ col,
                               const float* __restrict__ w, const float* __restrict__ dis,
                               const int* __restrict__ rowptr, const int* __restrict__ rank,
                               int2* __restrict__ ecn, int e)
{
    int i = blockIdx.x * blockDim.x + threadIdx.x;
    if (i < e) {
        int r = row[i], c = col[i];
        int pos = rowptr[r] + rank[i];
        float nv = -dis[r] * w[i] * dis[c];
        ecn[pos] = make_int2(c, __float_as_int(nv));
    }
}

// pad x [n][50] -> XH [n][64] fp16 (zeros beyond 50): gather tables are half the bytes
__global__ void padx_kernel(const float* __restrict__ x, __half* __restrict__ XH, int n64)
{
    int i = blockIdx.x * blockDim.x + threadIdx.x;
    if (i < n64) {
        int row = i >> 6, f = i & 63;
        XH[i] = __float2half((f < NF) ? x[row * NF + f] : 0.f);
    }
}

// ---------------------------------------------------------------- propagate (pure gather)
// One wave per row, lane = feature, ZERO LDS, fp16 gather tables.
// Masked unroll-16 with 16 independent accumulators: 16 gather instructions in
// flight per wave (2x R14) -- Little's-law lever for the latency-bound gathers.
// BS: base stride for fused T2 = 2*acc - base (0 = off; 50 = x masked; 64 = full).
template<int BS, bool SHADOW>
__global__ __launch_bounds__(256) void prop_kernel(
    const __half* __restrict__ xin, const float* __restrict__ base,
    const int* __restrict__ rowptr, const int* __restrict__ cnt,
    const int2* __restrict__ ecn, float* __restrict__ yout,
    __half* __restrict__ ysh, int n)
{
    int gw = (blockIdx.x * blockDim.x + threadIdx.x) >> 6;
    int lane = threadIdx.x & 63;
    if (gw >= n) return;
    int st = __builtin_amdgcn_readfirstlane(rowptr[gw]);
    int m  = __builtin_amdgcn_readfirstlane(cnt[gw]);
    float a[16];
    #pragma unroll
    for (int k = 0; k < 16; ++k) a[k] = 0.f;
    for (int t = 0; t < m; t += 16) {
        #pragma unroll
        for (int k = 0; k < 16; ++k) {
            int tk = t + k;
            int idx = st + min(tk, m - 1);             // clamped: valid when m>=1
            int2 md = ecn[idx];                        // uniform addr -> scalar load
            float nv = (tk < m) ? __int_as_float(md.y) : 0.f;
            a[k] += nv * __half2float(xin[md.x * C1 + lane]);
        }
    }
    float s01 = (a[0] + a[1]) + (a[2] + a[3]);
    float s23 = (a[4] + a[5]) + (a[6] + a[7]);
    float s45 = (a[8] + a[9]) + (a[10] + a[11]);
    float s67 = (a[12] + a[13]) + (a[14] + a[15]);
    float acc = (s01 + s23) + (s45 + s67);
    if (BS > 0) {   // T2 = 2*prop - base  (m==0: -base, correct)
        float bv = (BS == C1 || lane < BS) ? base[(size_t)gw * BS + lane] : 0.f;
        acc = 2.f * acc - bv;
    }
    yout[(size_t)gw * C1 + lane] = acc;
    if (SHADOW) ysh[(size_t)gw * C1 + lane] = __float2half(acc);
}

// ---------------------------------------------------------------- dense conv1 (+BN stats)
// h = relu(x@W0 + T1@W1 + T2@W2 + b1); h IN PLACE over T1 (row-local).
// Measured-best structure (R9): W in LDS [tap][f/4][j][4]; rows staged coalesced in
// per-wave LDS, read back as same-address b128 broadcasts. All fp32.
__global__ __launch_bounds__(512) void dense1_kernel(
    const float* __restrict__ x, float* U /*T1 in, h out*/, const float* __restrict__ T2,
    const float* __restrict__ W1, const float* __restrict__ b1,
    float* __restrict__ stats, int n)
{
    __shared__ __align__(16) float WI[3 * 13 * 64 * 4];   // 39936 B
    __shared__ __align__(16) float ROWS[8 * 4 * 3 * 64];  // 24576 B
    __shared__ float red[2][8][64];                       // 4 KB
    const int tid = threadIdx.x;
    for (int i = tid; i < 3 * 13 * 64 * 4; i += 512) WI[i] = 0.f;
    __syncthreads();
    for (int i = tid; i < 3 * NF * C1; i += 512) {
        int tap = i / (NF * C1), rem = i % (NF * C1), f = rem / C1, j = rem % C1;
        WI[((tap * 13 + (f >> 2)) * 64 + j) * 4 + (f & 3)] = W1[i];
    }
    __syncthreads();

    const int lane = tid & 63;
    const int wv   = tid >> 6;
    const int gw   = blockIdx.x * 8 + wv;
    const int rstep = gridDim.x * 8 * 4;
    const float bias = b1[lane];
    const float4* W4 = (const float4*)WI;
    const float4* R4 = (const float4*)ROWS;
    float ssum = 0.f, ssq = 0.f;

    for (int r0 = gw * 4; r0 < n; r0 += rstep) {
        const int nr = min(4, n - r0);
        // stage this wave's 4 rows x 3 tables (coalesced); same-wave use, no barrier
        #pragma unroll
        for (int r = 0; r < 4; ++r) {
            int row = min(r0 + r, n - 1);
            ROWS[((wv * 4 + r) * 3 + 0) * 64 + lane] = (lane < NF) ? x[row * NF + lane] : 0.f;
            ROWS[((wv * 4 + r) * 3 + 1) * 64 + lane] = U [row * C1 + lane];
            ROWS[((wv * 4 + r) * 3 + 2) * 64 + lane] = T2[row * C1 + lane];
        }
        float acc[4] = {bias, bias, bias, bias};
        for (int c = 0; c < 13; ++c) {
            float4 w0 = W4[(0 * 13 + c) * 64 + lane];
            float4 w1 = W4[(1 * 13 + c) * 64 + lane];
            float4 w2 = W4[(2 * 13 + c) * 64 + lane];
            #pragma unroll
            for (int r = 0; r < 4; ++r) {
                float4 t0 = R4[((wv * 4 + r) * 3 + 0) * 16 + c];   // broadcast
                float4 t1 = R4[((wv * 4 + r) * 3 + 1) * 16 + c];
                float4 t2 = R4[((wv * 4 + r) * 3 + 2) * 16 + c];
                acc[r] += t0.x * w0.x + t0.y * w0.y + t0.z * w0.z + t0.w * w0.w
                        + t1.x * w1.x + t1.y * w1.y + t1.z * w1.z + t1.w * w1.w
                        + t2.x * w2.x + t2.y * w2.y + t2.z * w2.z + t2.w * w2.w;
            }
        }
        #pragma unroll
        for (int r = 0; r < 4; ++r) {
            if (r < nr) {
                float v = fmaxf(acc[r], 0.f);
                U[(r0 + r) * C1 + lane] = v;       // in-place: own rows only
                ssum += v; ssq += v * v;
            }
        }
    }
    red[0][wv][lane] = ssum;
    red[1][wv][lane] = ssq;
    __syncthreads();
    if (tid < 128) {
        int which = tid >> 6, j = tid & 63;
        float tot = 0.f;
        #pragma unroll
        for (int wq = 0; wq < 8; ++wq) tot += red[which][wq][j];
        atomicAdd(&stats[which * 64 + j], tot);
    }
}

// ---------------------------------------------------------------- batch norm
__global__ void bn_finalize_kernel(float* __restrict__ stats, const float* __restrict__ gamma,
                                   const float* __restrict__ beta, float inv_n)
{
    int j = threadIdx.x;
    if (j < 64) {
        float mu   = stats[j] * inv_n;
        float var  = stats[64 + j] * inv_n - mu * mu;
        float rstd = 1.f / sqrtf(var + 1e-5f);
        float sc   = gamma[j] * rstd;
        stats[128 + j] = sc;
        stats[192 + j] = beta[j] - mu * sc;
    }
}

// BN in-place on fp32 h; also emits the fp16 shadow HH for conv2's gathers.
__global__ void bn_apply_kernel(float* __restrict__ h, __half2* __restrict__ hh,
                                const float* __restrict__ stats, int n4)
{
    int i = blockIdx.x * blockDim.x + threadIdx.x;
    const int stride = gridDim.x * blockDim.x;      // multiple of 16 -> j0 invariant
    int j0 = (i * 4) & 63;
    float s0 = stats[128 + j0], s1 = stats[129 + j0], s2 = stats[130 + j0], s3 = stats[131 + j0];
    float b0 = stats[192 + j0], b1 = stats[193 + j0], b2 = stats[194 + j0], b3 = stats[195 + j0];
    float4* h4 = (float4*)h;
    for (; i < n4; i += stride) {
        float4 v = h4[i];
        v.x = v.x * s0 + b0;
        v.y = v.y * s1 + b1;
        v.z = v.z * s2 + b2;
        v.w = v.w * s3 + b3;
        h4[i] = v;
        hh[i * 2 + 0] = __floats2half2_rn(v.x, v.y);
        hh[i * 2 + 1] = __floats2half2_rn(v.z, v.w);
    }
}

// ---------------------------------------------------------------- dense conv2 + final linear
// g = relu(hb@W0 + Q1@W1 + T2'@W2 + b2);  out = g @ linW^T + linb   (all fp32)
__global__ __launch_bounds__(512) void dense2_kernel(
    const float* __restrict__ hb, const float* __restrict__ Q1, const float* __restrict__ T2,
    const float* __restrict__ W2, const float* __restrict__ b2,
    const float* __restrict__ linW, const float* __restrict__ linb,
    float* __restrict__ out, int n)
{
    __shared__ __align__(16) float WI[3 * 16 * 64 * 4];   // 49152 B
    __shared__ __align__(16) float ROWS[8 * 4 * 3 * 64];  // 24576 B (gbuf reuses per-wave slice)
    __shared__ float LWT[C1 * OUTF];                      // 4 KB, [j][o]
    const int tid = threadIdx.x;
    for (int i = tid; i < 3 * C1 * C1; i += 512) {
        int tap = i / (C1 * C1), rem = i % (C1 * C1), f = rem / C1, j = rem % C1;
        WI[((tap * 16 + (f >> 2)) * 64 + j) * 4 + (f & 3)] = W2[i];
    }
    for (int i = tid; i < C1 * OUTF; i += 512) {
        int j = i / OUTF, o = i % OUTF;
        LWT[i] = linW[o * C1 + j];
    }
    __syncthreads();

    const int lane = tid & 63;
    const int wv   = tid >> 6;
    const int gw   = blockIdx.x * 8 + wv;
    const int rstep = gridDim.x * 8 * 4;
    const float bias = b2[lane];
    const float lb   = linb[lane & 15];
    const int rsel = lane >> 4, osel = lane & 15;
    const float4* W4 = (const float4*)WI;
    const float4* R4 = (const float4*)ROWS;
    float* gb = &ROWS[wv * (4 * 3 * 64)];   // per-wave gbuf: 4 rows x 72 <= 768 floats

    for (int r0 = gw * 4; r0 < n; r0 += rstep) {
        const int nr = min(4, n - r0);
        #pragma unroll
        for (int r = 0; r < 4; ++r) {
            int row = min(r0 + r, n - 1);
            ROWS[((wv * 4 + r) * 3 + 0) * 64 + lane] = hb[row * C1 + lane];
            ROWS[((wv * 4 + r) * 3 + 1) * 64 + lane] = Q1[row * C1 + lane];
            ROWS[((wv * 4 + r) * 3 + 2) * 64 + lane] = T2[row * C1 + lane];
        }
        float acc[4] = {bias, bias, bias, bias};
        for (int c = 0; c < 16; ++c) {
            float4 w0 = W4[(0 * 16 + c) * 64 + lane];
            float4 w1 = W4[(1 * 16 + c) * 64 + lane];
            float4 w2 = W4[(2 * 16 + c) * 64 + lane];
            #pragma unroll
            for (int r = 0; r < 4; ++r) {
                float4 t0 = R4[((wv * 4 + r) * 3 + 0) * 16 + c];   // broadcast
                float4 t1 = R4[((wv * 4 + r) * 3 + 1) * 16 + c];
                float4 t2 = R4[((wv * 4 + r) * 3 + 2) * 16 + c];
                acc[r] += t0.x * w0.x + t0.y * w0.y + t0.z * w0.z + t0.w * w0.w
                        + t1.x * w1.x + t1.y * w1.y + t1.z * w1.z + t1.w * w1.w
                        + t2.x * w2.x + t2.y * w2.y + t2.z * w2.z + t2.w * w2.w;
            }
        }
        // rows consumed; reuse this wave's ROWS slice as gbuf (same-wave DS in-order)
        #pragma unroll
        for (int r = 0; r < 4; ++r)
            gb[r * 72 + lane] = (r < nr) ? fmaxf(acc[r], 0.f) : 0.f;
        float oa = lb;
        #pragma unroll 8
        for (int j = 0; j < C1; ++j)
            oa += gb[rsel * 72 + j] * LWT[j * OUTF + osel];
        int rw = r0 + rsel;
        if (rw < n) out[rw * OUTF + osel] = oa;   // contiguous 256B store per wave
    }
}

// ---------------------------------------------------------------- launch
extern "C" void kernel_launch(void* const* d_in, const int* in_sizes, int n_in,
                              void* d_out, int out_size, void* d_ws, size_t ws_size,
                              hipStream_t stream)
{
    const float* x     = (const float*)d_in[0];
    const int*   ei    = (const int*)  d_in[1];
    const float* ew    = (const float*)d_in[2];
    const float* W1    = (const float*)d_in[3];
    const float* b1    = (const float*)d_in[4];
    const float* W2    = (const float*)d_in[5];
    const float* b2    = (const float*)d_in[6];
    const float* gamma = (const float*)d_in[7];
    const float* beta  = (const float*)d_in[8];
    const float* linW  = (const float*)d_in[9];
    const float* linb  = (const float*)d_in[10];
    float* out = (float*)d_out;
    (void)n_in; (void)out_size; (void)ws_size;

    const int n = in_sizes[0] / NF;    // 100000
    const int e = in_sizes[2];         // 1600000
    const int* row = ei;
    const int* col = ei + e;

    char* ws = (char*)d_ws;
    size_t off = 0;
    auto alloc = [&](size_t bytes) -> void* {
        void* p = ws + off;
        off += (bytes + 255) & ~(size_t)255;
        return p;
    };
    unsigned long long* pcd = (unsigned long long*)alloc((size_t)n * 8);
    float*  dis    = (float*)alloc((size_t)n * 4);
    int*    cnt    = (int*)  alloc((size_t)n * 4);
    int*    rowptr = (int*)  alloc((size_t)n * 4);
    int*    rank   = (int*)  alloc((size_t)e * 4);
    int*    bsum   = (int*)  alloc(256 * 4);
    float*  stats  = (float*)alloc(256 * 4);        // [sum|sumsq|scale|shift] x 64
    int2*   ecn    = (int2*) alloc((size_t)e * 8);  // interleaved (col, norm)
    __half* XH     = (__half*)alloc((size_t)n * C1 * 2);   // fp16 padded x
    __half* T1H    = (__half*)alloc((size_t)n * C1 * 2);   // fp16 shadow of T1
    __half* HH     = (__half*)alloc((size_t)n * C1 * 2);   // fp16 shadow of hb
    __half* Q1H    = (__half*)alloc((size_t)n * C1 * 2);   // fp16 shadow of Q1
    float*  U      = (float*)alloc((size_t)n * C1 * 4);    // T1, then h/hb (in-place)
    float*  H      = (float*)alloc((size_t)n * C1 * 4);    // T2, then Q1
    float*  S      = (float*)alloc((size_t)n * C1 * 4);    // T2' (conv2)

    hipMemsetAsync(pcd,   0, (size_t)n * 8, stream);
    hipMemsetAsync(stats, 0, 256 * 4, stream);

    const int eb  = (e + 255) / 256;
    const int nbk = (n + 255) / 256;
    pass1_kernel<<<eb, 256, 0, stream>>>(row, ew, pcd, rank, e);
    dis_kernel<<<nbk, 256, 0, stream>>>(pcd, dis, cnt, n);
    padx_kernel<<<(n * C1 + 255) / 256, 256, 0, stream>>>(x, XH, n * C1);

    const int nb = (n + SCAN_T * SCAN_I - 1) / (SCAN_T * SCAN_I);   // 98 <= 256
    scan_partial<<<nb, SCAN_T, 0, stream>>>(cnt, bsum, n);
    scan_bsums<<<1, 256, 0, stream>>>(bsum, nb);
    scan_final<<<nb, SCAN_T, 0, stream>>>(cnt, bsum, rowptr, n);
    scatter_kernel<<<eb, 256, 0, stream>>>(row, col, ew, dis, rowptr, rank, ecn, e);

    const int pb = (n + 3) / 4;   // one wave per row, 4 waves/block

    // conv1: T1 = prop(XH) -> U (+T1H); T2 = 2*prop(T1H) - x -> H; h = relu(dense) in U (+BN)
    prop_kernel<0,  true ><<<pb, 256, 0, stream>>>(XH,  x, rowptr, cnt, ecn, U, T1H, n);
    prop_kernel<NF, false><<<pb, 256, 0, stream>>>(T1H, x, rowptr, cnt, ecn, H, T1H, n);
    dense1_kernel<<<1024, 512, 0, stream>>>(x, U, H, W1, b1, stats, n);
    bn_finalize_kernel<<<1, 64, 0, stream>>>(stats, gamma, beta, 1.f / (float)n);
    bn_apply_kernel<<<2048, 256, 0, stream>>>(U, (__half2*)HH, stats, n * C1 / 4);

    // conv2: Q1 = prop(HH) -> H (+Q1H); T2' = 2*prop(Q1H) - hb -> S; out = dense+linear
    prop_kernel<0,  true ><<<pb, 256, 0, stream>>>(HH,  U, rowptr, cnt, ecn, H, Q1H, n);
    prop_kernel<C1, false><<<pb, 256, 0, stream>>>(Q1H, U, rowptr, cnt, ecn, S, Q1H, n);
    dense2_kernel<<<1024, 512, 0, stream>>>(U, H, S, W2, b2, linW, linb, out, n);
}

// Round 20
// 518.013 us; speedup vs baseline: 1.0139x; 1.0139x over previous
//
#include <hip/hip_runtime.h>
#include <hip/hip_bf16.h>
#include <hip/hip_fp16.h>

static constexpr int NF   = 50;   // input features
static constexpr int C1   = 64;   // conv1/conv2 channels
static constexpr int OUTF = 16;   // final output features
static constexpr int SCAN_T = 256;
static constexpr int SCAN_I = 4;
static constexpr float DEG_SCALE   = 8388608.f;      // 2^23 fixed-point for packed deg
static constexpr float DEG_INV     = 1.f / 8388608.f;

// ---------------------------------------------------------------- CSR build
// ONE packed 64-bit atomic per edge: high word = edge count, low word = fixed-point
// weighted degree. Returned old high word = this edge's rank within its row.
__global__ void pass1_kernel(const int* __restrict__ row, const float* __restrict__ w,
                             unsigned long long* __restrict__ pcd, int* __restrict__ rank, int e)
{
    int i = blockIdx.x * blockDim.x + threadIdx.x;
    if (i < e) {
        int r = row[i];
        unsigned int wq = (unsigned int)(w[i] * DEG_SCALE + 0.5f);
        unsigned long long pk = (1ULL << 32) | (unsigned long long)wq;
        unsigned long long old = atomicAdd(&pcd[r], pk);
        rank[i] = (int)(old >> 32);
    }
}

__global__ void dis_kernel(const unsigned long long* __restrict__ pcd,
                           float* __restrict__ dis, int* __restrict__ cnt, int n)
{
    int i = blockIdx.x * blockDim.x + threadIdx.x;
    if (i < n) {
        unsigned long long pk = pcd[i];
        int c = (int)(pk >> 32);
        float d = (float)(unsigned int)(pk & 0xFFFFFFFFu) * DEG_INV;
        cnt[i] = c;
        dis[i] = (d > 0.f) ? (1.f / sqrtf(d)) : 0.f;
    }
}

__global__ void scan_partial(const int* __restrict__ cnt, int* __restrict__ bsum, int n)
{
    __shared__ int sm[SCAN_T];
    int t = threadIdx.x;
    int base = blockIdx.x * SCAN_T * SCAN_I + t * SCAN_I;
    int s = 0;
    #pragma unroll
    for (int k = 0; k < SCAN_I; ++k) { int i = base + k; if (i < n) s += cnt[i]; }
    sm[t] = s; __syncthreads();
    for (int off = SCAN_T / 2; off > 0; off >>= 1) {
        if (t < off) sm[t] += sm[t + off];
        __syncthreads();
    }
    if (t == 0) bsum[blockIdx.x] = sm[0];
}

// single block; requires nb <= 256 (here nb = 98)
__global__ void scan_bsums(int* __restrict__ bsum, int nb)
{
    __shared__ int sm[256];
    int t = threadIdx.x;
    sm[t] = (t < nb) ? bsum[t] : 0;
    __syncthreads();
    for (int off = 1; off < 256; off <<= 1) {
        int v = (t >= off) ? sm[t - off] : 0;
        __syncthreads();
        sm[t] += v;
        __syncthreads();
    }
    if (t < nb) bsum[t] = (t == 0) ? 0 : sm[t - 1];   // exclusive
}

__global__ void scan_final(const int* __restrict__ cnt, const int* __restrict__ bsum,
                           int* __restrict__ rowptr, int n)
{
    __shared__ int sm[SCAN_T];
    int t = threadIdx.x;
    int base = blockIdx.x * SCAN_T * SCAN_I + t * SCAN_I;
    int v[SCAN_I]; int s = 0;
    #pragma unroll
    for (int k = 0; k < SCAN_I; ++k) { int i = base + k; v[k] = (i < n) ? cnt[i] : 0; s += v[k]; }
    sm[t] = s; __syncthreads();
    for (int off = 1; off < SCAN_T; off <<= 1) {
        int x = (t >= off) ? sm[t - off] : 0;
        __syncthreads();
        sm[t] += x;
        __syncthreads();
    }
    int pref = bsum[blockIdx.x] + sm[t] - s;   // thread-exclusive prefix
    #pragma unroll
    for (int k = 0; k < SCAN_I; ++k) {
        int i = base + k;
        if (i < n) { rowptr[i] = pref; pref += v[k]; }
    }
}

// atomic-free scatter: pos = rowptr[row] + rank. Writes interleaved (col, norm) int2.
__global__ void scatter_kernel(const int* __restrict__ row, const int* __restrict__ col,
                               const float* __restrict__ w, const float* __restrict__ dis,
                               const int* __restrict__ rowptr, const int* __restrict__ rank,
                               int2* __restrict__ ecn, int e)
{
    int i = blockIdx.x * blockDim.x + threadIdx.x;
    if (i < e) {
        int r = row[i], c = col[i];
        int pos = rowptr[r] + rank[i];
        float nv = -dis[r] * w[i] * dis[c];
        ecn[pos] = make_int2(c, __float_as_int(nv));
    }
}

// pad x [n][50] -> XH [n][64] fp16 (zeros beyond 50): gather tables are half the bytes
__global__ void padx_kernel(const float* __restrict__ x, __half* __restrict__ XH, int n64)
{
    int i = blockIdx.x * blockDim.x + threadIdx.x;
    if (i < n64) {
        int row = i >> 6, f = i & 63;
        XH[i] = __float2half((f < NF) ? x[row * NF + f] : 0.f);
    }
}

// ---------------------------------------------------------------- propagate (pure gather)
// One wave per row, lane = feature, ZERO LDS, fp16 gather tables (128B/row on the
// fabric); accumulate fp32; write fp32 result (+ fp16 shadow if a later prop gathers
// it). Masked unroll-8 (measured-best: R14 = 518us).
// BS: base stride for fused T2 = 2*acc - base (0 = off; 50 = x masked; 64 = full).
template<int BS, bool SHADOW>
__global__ __launch_bounds__(256) void prop_kernel(
    const __half* __restrict__ xin, const float* __restrict__ base,
    const int* __restrict__ rowptr, const int* __restrict__ cnt,
    const int2* __restrict__ ecn, float* __restrict__ yout,
    __half* __restrict__ ysh, int n)
{
    int gw = (blockIdx.x * blockDim.x + threadIdx.x) >> 6;
    int lane = threadIdx.x & 63;
    if (gw >= n) return;
    int st = __builtin_amdgcn_readfirstlane(rowptr[gw]);
    int m  = __builtin_amdgcn_readfirstlane(cnt[gw]);
    float a[8] = {0.f, 0.f, 0.f, 0.f, 0.f, 0.f, 0.f, 0.f};
    for (int t = 0; t < m; t += 8) {
        #pragma unroll
        for (int k = 0; k < 8; ++k) {
            int tk = t + k;
            int idx = st + min(tk, m - 1);             // clamped: valid when m>=1
            int2 md = ecn[idx];
            float nv = (tk < m) ? __int_as_float(md.y) : 0.f;
            a[k] += nv * __half2float(xin[md.x * C1 + lane]);
        }
    }
    float acc = ((a[0] + a[1]) + (a[2] + a[3])) + ((a[4] + a[5]) + (a[6] + a[7]));
    if (BS > 0) {   // T2 = 2*prop - base  (m==0: -base, correct)
        float bv = (BS == C1 || lane < BS) ? base[(size_t)gw * BS + lane] : 0.f;
        acc = 2.f * acc - bv;
    }
    yout[(size_t)gw * C1 + lane] = acc;
    if (SHADOW) ysh[(size_t)gw * C1 + lane] = __float2half(acc);
}

// ---------------------------------------------------------------- dense conv1 (+BN stats)
// h = relu(x@W0 + T1@W1 + T2@W2 + b1); h IN PLACE over T1 (row-local).
// Measured-best structure (R9): W in LDS [tap][f/4][j][4]; rows staged coalesced in
// per-wave LDS, read back as same-address b128 broadcasts. All fp32.
__global__ __launch_bounds__(512) void dense1_kernel(
    const float* __restrict__ x, float* U /*T1 in, h out*/, const float* __restrict__ T2,
    const float* __restrict__ W1, const float* __restrict__ b1,
    float* __restrict__ stats, int n)
{
    __shared__ __align__(16) float WI[3 * 13 * 64 * 4];   // 39936 B
    __shared__ __align__(16) float ROWS[8 * 4 * 3 * 64];  // 24576 B
    __shared__ float red[2][8][64];                       // 4 KB
    const int tid = threadIdx.x;
    for (int i = tid; i < 3 * 13 * 64 * 4; i += 512) WI[i] = 0.f;
    __syncthreads();
    for (int i = tid; i < 3 * NF * C1; i += 512) {
        int tap = i / (NF * C1), rem = i % (NF * C1), f = rem / C1, j = rem % C1;
        WI[((tap * 13 + (f >> 2)) * 64 + j) * 4 + (f & 3)] = W1[i];
    }
    __syncthreads();

    const int lane = tid & 63;
    const int wv   = tid >> 6;
    const int gw   = blockIdx.x * 8 + wv;
    const int rstep = gridDim.x * 8 * 4;
    const float bias = b1[lane];
    const float4* W4 = (const float4*)WI;
    const float4* R4 = (const float4*)ROWS;
    float ssum = 0.f, ssq = 0.f;

    for (int r0 = gw * 4; r0 < n; r0 += rstep) {
        const int nr = min(4, n - r0);
        // stage this wave's 4 rows x 3 tables (coalesced); same-wave use, no barrier
        #pragma unroll
        for (int r = 0; r < 4; ++r) {
            int row = min(r0 + r, n - 1);
            ROWS[((wv * 4 + r) * 3 + 0) * 64 + lane] = (lane < NF) ? x[row * NF + lane] : 0.f;
            ROWS[((wv * 4 + r) * 3 + 1) * 64 + lane] = U [row * C1 + lane];
            ROWS[((wv * 4 + r) * 3 + 2) * 64 + lane] = T2[row * C1 + lane];
        }
        float acc[4] = {bias, bias, bias, bias};
        for (int c = 0; c < 13; ++c) {
            float4 w0 = W4[(0 * 13 + c) * 64 + lane];
            float4 w1 = W4[(1 * 13 + c) * 64 + lane];
            float4 w2 = W4[(2 * 13 + c) * 64 + lane];
            #pragma unroll
            for (int r = 0; r < 4; ++r) {
                float4 t0 = R4[((wv * 4 + r) * 3 + 0) * 16 + c];   // broadcast
                float4 t1 = R4[((wv * 4 + r) * 3 + 1) * 16 + c];
                float4 t2 = R4[((wv * 4 + r) * 3 + 2) * 16 + c];
                acc[r] += t0.x * w0.x + t0.y * w0.y + t0.z * w0.z + t0.w * w0.w
                        + t1.x * w1.x + t1.y * w1.y + t1.z * w1.z + t1.w * w1.w
                        + t2.x * w2.x + t2.y * w2.y + t2.z * w2.z + t2.w * w2.w;
            }
        }
        #pragma unroll
        for (int r = 0; r < 4; ++r) {
            if (r < nr) {
                float v = fmaxf(acc[r], 0.f);
                U[(r0 + r) * C1 + lane] = v;       // in-place: own rows only
                ssum += v; ssq += v * v;
            }
        }
    }
    red[0][wv][lane] = ssum;
    red[1][wv][lane] = ssq;
    __syncthreads();
    if (tid < 128) {
        int which = tid >> 6, j = tid & 63;
        float tot = 0.f;
        #pragma unroll
        for (int wq = 0; wq < 8; ++wq) tot += red[which][wq][j];
        atomicAdd(&stats[which * 64 + j], tot);
    }
}

// ---------------------------------------------------------------- batch norm
__global__ void bn_finalize_kernel(float* __restrict__ stats, const float* __restrict__ gamma,
                                   const float* __restrict__ beta, float inv_n)
{
    int j = threadIdx.x;
    if (j < 64) {
        float mu   = stats[j] * inv_n;
        float var  = stats[64 + j] * inv_n - mu * mu;
        float rstd = 1.f / sqrtf(var + 1e-5f);
        float sc   = gamma[j] * rstd;
        stats[128 + j] = sc;
        stats[192 + j] = beta[j] - mu * sc;
    }
}

// BN in-place on fp32 h; also emits the fp16 shadow HH for conv2's gathers.
__global__ void bn_apply_kernel(float* __restrict__ h, __half2* __restrict__ hh,
                                const float* __restrict__ stats, int n4)
{
    int i = blockIdx.x * blockDim.x + threadIdx.x;
    const int stride = gridDim.x * blockDim.x;      // multiple of 16 -> j0 invariant
    int j0 = (i * 4) & 63;
    float s0 = stats[128 + j0], s1 = stats[129 + j0], s2 = stats[130 + j0], s3 = stats[131 + j0];
    float b0 = stats[192 + j0], b1 = stats[193 + j0], b2 = stats[194 + j0], b3 = stats[195 + j0];
    float4* h4 = (float4*)h;
    for (; i < n4; i += stride) {
        float4 v = h4[i];
        v.x = v.x * s0 + b0;
        v.y = v.y * s1 + b1;
        v.z = v.z * s2 + b2;
        v.w = v.w * s3 + b3;
        h4[i] = v;
        hh[i * 2 + 0] = __floats2half2_rn(v.x, v.y);
        hh[i * 2 + 1] = __floats2half2_rn(v.z, v.w);
    }
}

// ---------------------------------------------------------------- dense conv2 + final linear
// g = relu(hb@W0 + Q1@W1 + T2'@W2 + b2);  out = g @ linW^T + linb   (all fp32)
__global__ __launch_bounds__(512) void dense2_kernel(
    const float* __restrict__ hb, const float* __restrict__ Q1, const float* __restrict__ T2,
    const float* __restrict__ W2, const float* __restrict__ b2,
    const float* __restrict__ linW, const float* __restrict__ linb,
    float* __restrict__ out, int n)
{
    __shared__ __align__(16) float WI[3 * 16 * 64 * 4];   // 49152 B
    __shared__ __align__(16) float ROWS[8 * 4 * 3 * 64];  // 24576 B (gbuf reuses per-wave slice)
    __shared__ float LWT[C1 * OUTF];                      // 4 KB, [j][o]
    const int tid = threadIdx.x;
    for (int i = tid; i < 3 * C1 * C1; i += 512) {
        int tap = i / (C1 * C1), rem = i % (C1 * C1), f = rem / C1, j = rem % C1;
        WI[((tap * 16 + (f >> 2)) * 64 + j) * 4 + (f & 3)] = W2[i];
    }
    for (int i = tid; i < C1 * OUTF; i += 512) {
        int j = i / OUTF, o = i % OUTF;
        LWT[i] = linW[o * C1 + j];
    }
    __syncthreads();

    const int lane = tid & 63;
    const int wv   = tid >> 6;
    const int gw   = blockIdx.x * 8 + wv;
    const int rstep = gridDim.x * 8 * 4;
    const float bias = b2[lane];
    const float lb   = linb[lane & 15];
    const int rsel = lane >> 4, osel = lane & 15;
    const float4* W4 = (const float4*)WI;
    const float4* R4 = (const float4*)ROWS;
    float* gb = &ROWS[wv * (4 * 3 * 64)];   // per-wave gbuf: 4 rows x 72 <= 768 floats

    for (int r0 = gw * 4; r0 < n; r0 += rstep) {
        const int nr = min(4, n - r0);
        #pragma unroll
        for (int r = 0; r < 4; ++r) {
            int row = min(r0 + r, n - 1);
            ROWS[((wv * 4 + r) * 3 + 0) * 64 + lane] = hb[row * C1 + lane];
            ROWS[((wv * 4 + r) * 3 + 1) * 64 + lane] = Q1[row * C1 + lane];
            ROWS[((wv * 4 + r) * 3 + 2) * 64 + lane] = T2[row * C1 + lane];
        }
        float acc[4] = {bias, bias, bias, bias};
        for (int c = 0; c < 16; ++c) {
            float4 w0 = W4[(0 * 16 + c) * 64 + lane];
            float4 w1 = W4[(1 * 16 + c) * 64 + lane];
            float4 w2 = W4[(2 * 16 + c) * 64 + lane];
            #pragma unroll
            for (int r = 0; r < 4; ++r) {
                float4 t0 = R4[((wv * 4 + r) * 3 + 0) * 16 + c];   // broadcast
                float4 t1 = R4[((wv * 4 + r) * 3 + 1) * 16 + c];
                float4 t2 = R4[((wv * 4 + r) * 3 + 2) * 16 + c];
                acc[r] += t0.x * w0.x + t0.y * w0.y + t0.z * w0.z + t0.w * w0.w
                        + t1.x * w1.x + t1.y * w1.y + t1.z * w1.z + t1.w * w1.w
                        + t2.x * w2.x + t2.y * w2.y + t2.z * w2.z + t2.w * w2.w;
            }
        }
        // rows consumed; reuse this wave's ROWS slice as gbuf (same-wave DS in-order)
        #pragma unroll
        for (int r = 0; r < 4; ++r)
            gb[r * 72 + lane] = (r < nr) ? fmaxf(acc[r], 0.f) : 0.f;
        float oa = lb;
        #pragma unroll 8
        for (int j = 0; j < C1; ++j)
            oa += gb[rsel * 72 + j] * LWT[j * OUTF + osel];
        int rw = r0 + rsel;
        if (rw < n) out[rw * OUTF + osel] = oa;   // contiguous 256B store per wave
    }
}

// ---------------------------------------------------------------- launch
extern "C" void kernel_launch(void* const* d_in, const int* in_sizes, int n_in,
                              void* d_out, int out_size, void* d_ws, size_t ws_size,
                              hipStream_t stream)
{
    const float* x     = (const float*)d_in[0];
    const int*   ei    = (const int*)  d_in[1];
    const float* ew    = (const float*)d_in[2];
    const float* W1    = (const float*)d_in[3];
    const float* b1    = (const float*)d_in[4];
    const float* W2    = (const float*)d_in[5];
    const float* b2    = (const float*)d_in[6];
    const float* gamma = (const float*)d_in[7];
    const float* beta  = (const float*)d_in[8];
    const float* linW  = (const float*)d_in[9];
    const float* linb  = (const float*)d_in[10];
    float* out = (float*)d_out;
    (void)n_in; (void)out_size; (void)ws_size;

    const int n = in_sizes[0] / NF;    // 100000
    const int e = in_sizes[2];         // 1600000
    const int* row = ei;
    const int* col = ei + e;

    char* ws = (char*)d_ws;
    size_t off = 0;
    auto alloc = [&](size_t bytes) -> void* {
        void* p = ws + off;
        off += (bytes + 255) & ~(size_t)255;
        return p;
    };
    unsigned long long* pcd = (unsigned long long*)alloc((size_t)n * 8);
    float*  dis    = (float*)alloc((size_t)n * 4);
    int*    cnt    = (int*)  alloc((size_t)n * 4);
    int*    rowptr = (int*)  alloc((size_t)n * 4);
    int*    rank   = (int*)  alloc((size_t)e * 4);
    int*    bsum   = (int*)  alloc(256 * 4);
    float*  stats  = (float*)alloc(256 * 4);        // [sum|sumsq|scale|shift] x 64
    int2*   ecn    = (int2*) alloc((size_t)e * 8);  // interleaved (col, norm)
    __half* XH     = (__half*)alloc((size_t)n * C1 * 2);   // fp16 padded x
    __half* T1H    = (__half*)alloc((size_t)n * C1 * 2);   // fp16 shadow of T1
    __half* HH     = (__half*)alloc((size_t)n * C1 * 2);   // fp16 shadow of hb
    __half* Q1H    = (__half*)alloc((size_t)n * C1 * 2);   // fp16 shadow of Q1
    float*  U      = (float*)alloc((size_t)n * C1 * 4);    // T1, then h/hb (in-place)
    float*  H      = (float*)alloc((size_t)n * C1 * 4);    // T2, then Q1
    float*  S      = (float*)alloc((size_t)n * C1 * 4);    // T2' (conv2)

    hipMemsetAsync(pcd,   0, (size_t)n * 8, stream);
    hipMemsetAsync(stats, 0, 256 * 4, stream);

    const int eb  = (e + 255) / 256;
    const int nbk = (n + 255) / 256;
    pass1_kernel<<<eb, 256, 0, stream>>>(row, ew, pcd, rank, e);
    dis_kernel<<<nbk, 256, 0, stream>>>(pcd, dis, cnt, n);
    padx_kernel<<<(n * C1 + 255) / 256, 256, 0, stream>>>(x, XH, n * C1);

    const int nb = (n + SCAN_T * SCAN_I - 1) / (SCAN_T * SCAN_I);   // 98 <= 256
    scan_partial<<<nb, SCAN_T, 0, stream>>>(cnt, bsum, n);
    scan_bsums<<<1, 256, 0, stream>>>(bsum, nb);
    scan_final<<<nb, SCAN_T, 0, stream>>>(cnt, bsum, rowptr, n);
    scatter_kernel<<<eb, 256, 0, stream>>>(row, col, ew, dis, rowptr, rank, ecn, e);

    const int pb = (n + 3) / 4;   // one wave per row, 4 waves/block

    // conv1: T1 = prop(XH) -> U (+T1H); T2 = 2*prop(T1H) - x -> H; h = relu(dense) in U (+BN)
    prop_kernel<0,  true ><<<pb, 256, 0, stream>>>(XH,  x, rowptr, cnt, ecn, U, T1H, n);
    prop_kernel<NF, false><<<pb, 256, 0, stream>>>(T1H, x, rowptr, cnt, ecn, H, T1H, n);
    dense1_kernel<<<1024, 512, 0, stream>>>(x, U, H, W1, b1, stats, n);
    bn_finalize_kernel<<<1, 64, 0, stream>>>(stats, gamma, beta, 1.f / (float)n);
    bn_apply_kernel<<<2048, 256, 0, stream>>>(U, (__half2*)HH, stats, n * C1 / 4);

    // conv2: Q1 = prop(HH) -> H (+Q1H); T2' = 2*prop(Q1H) - hb -> S; out = dense+linear
    prop_kernel<0,  true ><<<pb, 256, 0, stream>>>(HH,  U, rowptr, cnt, ecn, H, Q1H, n);
    prop_kernel<C1, false><<<pb, 256, 0, stream>>>(Q1H, U, rowptr, cnt, ecn, S, Q1H, n);
    dense2_kernel<<<1024, 512, 0, stream>>>(U, H, S, W2, b2, linW, linb, out, n);
}

// Round 21
// 475.751 us; speedup vs baseline: 1.1040x; 1.0888x over previous
//
#include <hip/hip_runtime.h>
#include <hip/hip_bf16.h>
#include <hip/hip_fp16.h>

static constexpr int NF   = 50;   // input features
static constexpr int C1   = 64;   // conv1/conv2 channels
static constexpr int OUTF = 16;   // final output features
static constexpr int SCAN_T = 256;
static constexpr int SCAN_I = 4;
static constexpr float DEG_SCALE   = 8388608.f;      // 2^23 fixed-point for packed deg
static constexpr float DEG_INV     = 1.f / 8388608.f;

typedef _Float16 half8 __attribute__((ext_vector_type(8)));
typedef float    f32x4 __attribute__((ext_vector_type(4)));

// ---------------------------------------------------------------- CSR build
__global__ void pass1_kernel(const int* __restrict__ row, const float* __restrict__ w,
                             unsigned long long* __restrict__ pcd, int* __restrict__ rank, int e)
{
    int i = blockIdx.x * blockDim.x + threadIdx.x;
    if (i < e) {
        int r = row[i];
        unsigned int wq = (unsigned int)(w[i] * DEG_SCALE + 0.5f);
        unsigned long long pk = (1ULL << 32) | (unsigned long long)wq;
        unsigned long long old = atomicAdd(&pcd[r], pk);
        rank[i] = (int)(old >> 32);
    }
}

__global__ void dis_kernel(const unsigned long long* __restrict__ pcd,
                           float* __restrict__ dis, int* __restrict__ cnt, int n)
{
    int i = blockIdx.x * blockDim.x + threadIdx.x;
    if (i < n) {
        unsigned long long pk = pcd[i];
        int c = (int)(pk >> 32);
        float d = (float)(unsigned int)(pk & 0xFFFFFFFFu) * DEG_INV;
        cnt[i] = c;
        dis[i] = (d > 0.f) ? (1.f / sqrtf(d)) : 0.f;
    }
}

__global__ void scan_partial(const int* __restrict__ cnt, int* __restrict__ bsum, int n)
{
    __shared__ int sm[SCAN_T];
    int t = threadIdx.x;
    int base = blockIdx.x * SCAN_T * SCAN_I + t * SCAN_I;
    int s = 0;
    #pragma unroll
    for (int k = 0; k < SCAN_I; ++k) { int i = base + k; if (i < n) s += cnt[i]; }
    sm[t] = s; __syncthreads();
    for (int off = SCAN_T / 2; off > 0; off >>= 1) {
        if (t < off) sm[t] += sm[t + off];
        __syncthreads();
    }
    if (t == 0) bsum[blockIdx.x] = sm[0];
}

// single block; requires nb <= 256 (here nb = 98)
__global__ void scan_bsums(int* __restrict__ bsum, int nb)
{
    __shared__ int sm[256];
    int t = threadIdx.x;
    sm[t] = (t < nb) ? bsum[t] : 0;
    __syncthreads();
    for (int off = 1; off < 256; off <<= 1) {
        int v = (t >= off) ? sm[t - off] : 0;
        __syncthreads();
        sm[t] += v;
        __syncthreads();
    }
    if (t < nb) bsum[t] = (t == 0) ? 0 : sm[t - 1];   // exclusive
}

__global__ void scan_final(const int* __restrict__ cnt, const int* __restrict__ bsum,
                           int* __restrict__ rowptr, int n)
{
    __shared__ int sm[SCAN_T];
    int t = threadIdx.x;
    int base = blockIdx.x * SCAN_T * SCAN_I + t * SCAN_I;
    int v[SCAN_I]; int s = 0;
    #pragma unroll
    for (int k = 0; k < SCAN_I; ++k) { int i = base + k; v[k] = (i < n) ? cnt[i] : 0; s += v[k]; }
    sm[t] = s; __syncthreads();
    for (int off = 1; off < SCAN_T; off <<= 1) {
        int x = (t >= off) ? sm[t - off] : 0;
        __syncthreads();
        sm[t] += x;
        __syncthreads();
    }
    int pref = bsum[blockIdx.x] + sm[t] - s;   // thread-exclusive prefix
    #pragma unroll
    for (int k = 0; k < SCAN_I; ++k) {
        int i = base + k;
        if (i < n) { rowptr[i] = pref; pref += v[k]; }
    }
}

// atomic-free scatter: pos = rowptr[row] + rank. Writes interleaved (col, norm) int2.
__global__ void scatter_kernel(const int* __restrict__ row, const int* __restrict__ col,
                               const float* __restrict__ w, const float* __restrict__ dis,
                               const int* __restrict__ rowptr, const int* __restrict__ rank,
                               int2* __restrict__ ecn, int e)
{
    int i = blockIdx.x * blockDim.x + threadIdx.x;
    if (i < e) {
        int r = row[i], c = col[i];
        int pos = rowptr[r] + rank[i];
        float nv = -dis[r] * w[i] * dis[c];
        ecn[pos] = make_int2(c, __float_as_int(nv));
    }
}

// pad x [n][50] -> XH [n][64] fp16 (zeros beyond 50): gather tables are half the bytes
__global__ void padx_kernel(const float* __restrict__ x, __half* __restrict__ XH, int n64)
{
    int i = blockIdx.x * blockDim.x + threadIdx.x;
    if (i < n64) {
        int row = i >> 6, f = i & 63;
        XH[i] = __float2half((f < NF) ? x[row * NF + f] : 0.f);
    }
}

// transpose W2 [tap][k][col] fp32 -> WTh [tap][col][k] fp16 (MFMA B-frag contiguity)
__global__ void wprep_kernel(const float* __restrict__ W2, __half* __restrict__ WTh)
{
    int i = blockIdx.x * blockDim.x + threadIdx.x;
    if (i < 3 * C1 * C1) {
        int tap = i / (C1 * C1), rem = i % (C1 * C1), col = rem / C1, k = rem % C1;
        WTh[i] = __float2half(W2[tap * C1 * C1 + k * C1 + col]);
    }
}

// ---------------------------------------------------------------- propagate (pure gather)
// One wave per row, lane = feature, ZERO LDS, fp16 gather tables; masked unroll-8
// (measured-best R14). BS: base stride for fused T2 = 2*acc - base (0 = off).
template<int BS, bool SHADOW>
__global__ __launch_bounds__(256) void prop_kernel(
    const __half* __restrict__ xin, const float* __restrict__ base,
    const int* __restrict__ rowptr, const int* __restrict__ cnt,
    const int2* __restrict__ ecn, float* __restrict__ yout,
    __half* __restrict__ ysh, int n)
{
    int gw = (blockIdx.x * blockDim.x + threadIdx.x) >> 6;
    int lane = threadIdx.x & 63;
    if (gw >= n) return;
    int st = __builtin_amdgcn_readfirstlane(rowptr[gw]);
    int m  = __builtin_amdgcn_readfirstlane(cnt[gw]);
    float a[8] = {0.f, 0.f, 0.f, 0.f, 0.f, 0.f, 0.f, 0.f};
    for (int t = 0; t < m; t += 8) {
        #pragma unroll
        for (int k = 0; k < 8; ++k) {
            int tk = t + k;
            int idx = st + min(tk, m - 1);             // clamped: valid when m>=1
            int2 md = ecn[idx];
            float nv = (tk < m) ? __int_as_float(md.y) : 0.f;
            a[k] += nv * __half2float(xin[md.x * C1 + lane]);
        }
    }
    float acc = ((a[0] + a[1]) + (a[2] + a[3])) + ((a[4] + a[5]) + (a[6] + a[7]));
    if (BS > 0) {   // T2 = 2*prop - base  (m==0: -base, correct)
        float bv = (BS == C1 || lane < BS) ? base[(size_t)gw * BS + lane] : 0.f;
        acc = 2.f * acc - bv;
    }
    yout[(size_t)gw * C1 + lane] = acc;
    if (SHADOW) ysh[(size_t)gw * C1 + lane] = __float2half(acc);
}

// ---------------------------------------------------------------- dense conv1 (+BN stats)
// UNCHANGED measured-best R9 structure. h IN PLACE over T1 (row-local). All fp32.
__global__ __launch_bounds__(512) void dense1_kernel(
    const float* __restrict__ x, float* U /*T1 in, h out*/, const float* __restrict__ T2,
    const float* __restrict__ W1, const float* __restrict__ b1,
    float* __restrict__ stats, int n)
{
    __shared__ __align__(16) float WI[3 * 13 * 64 * 4];   // 39936 B
    __shared__ __align__(16) float ROWS[8 * 4 * 3 * 64];  // 24576 B
    __shared__ float red[2][8][64];                       // 4 KB
    const int tid = threadIdx.x;
    for (int i = tid; i < 3 * 13 * 64 * 4; i += 512) WI[i] = 0.f;
    __syncthreads();
    for (int i = tid; i < 3 * NF * C1; i += 512) {
        int tap = i / (NF * C1), rem = i % (NF * C1), f = rem / C1, j = rem % C1;
        WI[((tap * 13 + (f >> 2)) * 64 + j) * 4 + (f & 3)] = W1[i];
    }
    __syncthreads();

    const int lane = tid & 63;
    const int wv   = tid >> 6;
    const int gw   = blockIdx.x * 8 + wv;
    const int rstep = gridDim.x * 8 * 4;
    const float bias = b1[lane];
    const float4* W4 = (const float4*)WI;
    const float4* R4 = (const float4*)ROWS;
    float ssum = 0.f, ssq = 0.f;

    for (int r0 = gw * 4; r0 < n; r0 += rstep) {
        const int nr = min(4, n - r0);
        #pragma unroll
        for (int r = 0; r < 4; ++r) {
            int row = min(r0 + r, n - 1);
            ROWS[((wv * 4 + r) * 3 + 0) * 64 + lane] = (lane < NF) ? x[row * NF + lane] : 0.f;
            ROWS[((wv * 4 + r) * 3 + 1) * 64 + lane] = U [row * C1 + lane];
            ROWS[((wv * 4 + r) * 3 + 2) * 64 + lane] = T2[row * C1 + lane];
        }
        float acc[4] = {bias, bias, bias, bias};
        for (int c = 0; c < 13; ++c) {
            float4 w0 = W4[(0 * 13 + c) * 64 + lane];
            float4 w1 = W4[(1 * 13 + c) * 64 + lane];
            float4 w2 = W4[(2 * 13 + c) * 64 + lane];
            #pragma unroll
            for (int r = 0; r < 4; ++r) {
                float4 t0 = R4[((wv * 4 + r) * 3 + 0) * 16 + c];   // broadcast
                float4 t1 = R4[((wv * 4 + r) * 3 + 1) * 16 + c];
                float4 t2 = R4[((wv * 4 + r) * 3 + 2) * 16 + c];
                acc[r] += t0.x * w0.x + t0.y * w0.y + t0.z * w0.z + t0.w * w0.w
                        + t1.x * w1.x + t1.y * w1.y + t1.z * w1.z + t1.w * w1.w
                        + t2.x * w2.x + t2.y * w2.y + t2.z * w2.z + t2.w * w2.w;
            }
        }
        #pragma unroll
        for (int r = 0; r < 4; ++r) {
            if (r < nr) {
                float v = fmaxf(acc[r], 0.f);
                U[(r0 + r) * C1 + lane] = v;       // in-place: own rows only
                ssum += v; ssq += v * v;
            }
        }
    }
    red[0][wv][lane] = ssum;
    red[1][wv][lane] = ssq;
    __syncthreads();
    if (tid < 128) {
        int which = tid >> 6, j = tid & 63;
        float tot = 0.f;
        #pragma unroll
        for (int wq = 0; wq < 8; ++wq) tot += red[which][wq][j];
        atomicAdd(&stats[which * 64 + j], tot);
    }
}

// ---------------------------------------------------------------- batch norm
__global__ void bn_finalize_kernel(float* __restrict__ stats, const float* __restrict__ gamma,
                                   const float* __restrict__ beta, float inv_n)
{
    int j = threadIdx.x;
    if (j < 64) {
        float mu   = stats[j] * inv_n;
        float var  = stats[64 + j] * inv_n - mu * mu;
        float rstd = 1.f / sqrtf(var + 1e-5f);
        float sc   = gamma[j] * rstd;
        stats[128 + j] = sc;
        stats[192 + j] = beta[j] - mu * sc;
    }
}

// BN in-place on fp32 h; also emits the fp16 shadow HH for conv2's gathers + MFMA.
__global__ void bn_apply_kernel(float* __restrict__ h, __half2* __restrict__ hh,
                                const float* __restrict__ stats, int n4)
{
    int i = blockIdx.x * blockDim.x + threadIdx.x;
    const int stride = gridDim.x * blockDim.x;      // multiple of 16 -> j0 invariant
    int j0 = (i * 4) & 63;
    float s0 = stats[128 + j0], s1 = stats[129 + j0], s2 = stats[130 + j0], s3 = stats[131 + j0];
    float b0 = stats[192 + j0], b1 = stats[193 + j0], b2 = stats[194 + j0], b3 = stats[195 + j0];
    float4* h4 = (float4*)h;
    for (; i < n4; i += stride) {
        float4 v = h4[i];
        v.x = v.x * s0 + b0;
        v.y = v.y * s1 + b1;
        v.z = v.z * s2 + b2;
        v.w = v.w * s3 + b3;
        h4[i] = v;
        hh[i * 2 + 0] = __floats2half2_rn(v.x, v.y);
        hh[i * 2 + 1] = __floats2half2_rn(v.z, v.w);
    }
}

// ---------------------------------------------------------------- dense conv2 + final linear (MFMA)
// g = relu(hb@W0 + Q1@W1 + T2'@W2 + b2);  out = g @ linW^T + linb
// 16 rows per wave-tile; inputs fp16 (HH/Q1H/SH), weights fp16 transposed (WTh).
// A-frag: lane(row=l&15, k=(l>>4)*8..+8) 16B global load; B-frag same from WTh;
// C/D: col=lane&15, row=(lane>>4)*4+reg (guide-verified). Accumulate fp32.
__global__ __launch_bounds__(512) void dense2_kernel(
    const __half* __restrict__ hb16, const __half* __restrict__ q16,
    const __half* __restrict__ t16,  const __half* __restrict__ WTh,
    const float* __restrict__ b2, const float* __restrict__ linW,
    const float* __restrict__ linb, float* __restrict__ out, int n)
{
    __shared__ float LWT[C1 * OUTF];          // [j][o], 4 KB
    __shared__ float gst[8][16][65];          // 33.3 KB, pad 65: bank-spread rows
    const int tid = threadIdx.x;
    for (int i = tid; i < C1 * OUTF; i += 512) {
        int j = i / OUTF, o = i % OUTF;
        LWT[i] = linW[o * C1 + j];
    }
    __syncthreads();

    const int lane = tid & 63, wv = tid >> 6;
    const int cl = lane & 15, rg = lane >> 4;
    const int nt = n >> 4;                     // tiles of 16 rows (n % 16 == 0)
    const float lb = linb[cl];

    for (int tile = blockIdx.x * 8 + wv; tile < nt; tile += gridDim.x * 8) {
        int r0 = tile * 16;
        // A fragments: 3 taps x 2 k-steps, one 16B load each
        const __half* ta = hb16 + (size_t)(r0 + cl) * C1 + rg * 8;
        const __half* tb = q16  + (size_t)(r0 + cl) * C1 + rg * 8;
        const __half* tc = t16  + (size_t)(r0 + cl) * C1 + rg * 8;
        half8 a00 = *(const half8*)(ta);   half8 a01 = *(const half8*)(ta + 32);
        half8 a10 = *(const half8*)(tb);   half8 a11 = *(const half8*)(tb + 32);
        half8 a20 = *(const half8*)(tc);   half8 a21 = *(const half8*)(tc + 32);

        #pragma unroll
        for (int ct = 0; ct < 4; ++ct) {
            float bias = b2[ct * 16 + cl];
            f32x4 acc = {bias, bias, bias, bias};
            const __half* wb = WTh + (ct * 16 + cl) * C1 + rg * 8;   // B[k][col], k contiguous
            acc = __builtin_amdgcn_mfma_f32_16x16x32_f16(a00, *(const half8*)(wb),              acc, 0, 0, 0);
            acc = __builtin_amdgcn_mfma_f32_16x16x32_f16(a01, *(const half8*)(wb + 32),         acc, 0, 0, 0);
            acc = __builtin_amdgcn_mfma_f32_16x16x32_f16(a10, *(const half8*)(wb + 4096),       acc, 0, 0, 0);
            acc = __builtin_amdgcn_mfma_f32_16x16x32_f16(a11, *(const half8*)(wb + 4096 + 32),  acc, 0, 0, 0);
            acc = __builtin_amdgcn_mfma_f32_16x16x32_f16(a20, *(const half8*)(wb + 8192),       acc, 0, 0, 0);
            acc = __builtin_amdgcn_mfma_f32_16x16x32_f16(a21, *(const half8*)(wb + 8192 + 32),  acc, 0, 0, 0);
            #pragma unroll
            for (int r = 0; r < 4; ++r)
                gst[wv][rg * 4 + r][ct * 16 + cl] = fmaxf(acc[r], 0.f);   // C/D mapping
        }
        // same-wave DS in-order; final linear: lane covers rows r4*4+rg, out col cl
        #pragma unroll
        for (int r4 = 0; r4 < 4; ++r4) {
            int row = r4 * 4 + rg;
            float oa = lb;
            #pragma unroll 8
            for (int j = 0; j < C1; ++j)
                oa += gst[wv][row][j] * LWT[j * OUTF + cl];
            out[(size_t)(r0 + row) * OUTF + cl] = oa;   // 64B contiguous per rg group
        }
    }
}

// ---------------------------------------------------------------- launch
extern "C" void kernel_launch(void* const* d_in, const int* in_sizes, int n_in,
                              void* d_out, int out_size, void* d_ws, size_t ws_size,
                              hipStream_t stream)
{
    const float* x     = (const float*)d_in[0];
    const int*   ei    = (const int*)  d_in[1];
    const float* ew    = (const float*)d_in[2];
    const float* W1    = (const float*)d_in[3];
    const float* b1    = (const float*)d_in[4];
    const float* W2    = (const float*)d_in[5];
    const float* b2    = (const float*)d_in[6];
    const float* gamma = (const float*)d_in[7];
    const float* beta  = (const float*)d_in[8];
    const float* linW  = (const float*)d_in[9];
    const float* linb  = (const float*)d_in[10];
    float* out = (float*)d_out;
    (void)n_in; (void)out_size; (void)ws_size;

    const int n = in_sizes[0] / NF;    // 100000
    const int e = in_sizes[2];         // 1600000
    const int* row = ei;
    const int* col = ei + e;

    char* ws = (char*)d_ws;
    size_t off = 0;
    auto alloc = [&](size_t bytes) -> void* {
        void* p = ws + off;
        off += (bytes + 255) & ~(size_t)255;
        return p;
    };
    unsigned long long* pcd = (unsigned long long*)alloc((size_t)n * 8);
    float*  dis    = (float*)alloc((size_t)n * 4);
    int*    cnt    = (int*)  alloc((size_t)n * 4);
    int*    rowptr = (int*)  alloc((size_t)n * 4);
    int*    rank   = (int*)  alloc((size_t)e * 4);
    int*    bsum   = (int*)  alloc(256 * 4);
    float*  stats  = (float*)alloc(256 * 4);        // [sum|sumsq|scale|shift] x 64
    int2*   ecn    = (int2*) alloc((size_t)e * 8);  // interleaved (col, norm)
    __half* XH     = (__half*)alloc((size_t)n * C1 * 2);   // fp16 padded x
    __half* T1H    = (__half*)alloc((size_t)n * C1 * 2);   // fp16 shadow of T1
    __half* HH     = (__half*)alloc((size_t)n * C1 * 2);   // fp16 shadow of hb
    __half* Q1H    = (__half*)alloc((size_t)n * C1 * 2);   // fp16 shadow of Q1
    __half* SH     = (__half*)alloc((size_t)n * C1 * 2);   // fp16 shadow of T2'
    __half* WTh    = (__half*)alloc((size_t)3 * C1 * C1 * 2); // fp16 W2 transposed
    float*  U      = (float*)alloc((size_t)n * C1 * 4);    // T1, then h/hb (in-place)
    float*  H      = (float*)alloc((size_t)n * C1 * 4);    // T2, then Q1
    float*  S      = (float*)alloc((size_t)n * C1 * 4);    // T2' (conv2)

    hipMemsetAsync(pcd,   0, (size_t)n * 8, stream);
    hipMemsetAsync(stats, 0, 256 * 4, stream);

    const int eb  = (e + 255) / 256;
    const int nbk = (n + 255) / 256;
    pass1_kernel<<<eb, 256, 0, stream>>>(row, ew, pcd, rank, e);
    dis_kernel<<<nbk, 256, 0, stream>>>(pcd, dis, cnt, n);
    padx_kernel<<<(n * C1 + 255) / 256, 256, 0, stream>>>(x, XH, n * C1);
    wprep_kernel<<<(3 * C1 * C1 + 255) / 256, 256, 0, stream>>>(W2, WTh);

    const int nb = (n + SCAN_T * SCAN_I - 1) / (SCAN_T * SCAN_I);   // 98 <= 256
    scan_partial<<<nb, SCAN_T, 0, stream>>>(cnt, bsum, n);
    scan_bsums<<<1, 256, 0, stream>>>(bsum, nb);
    scan_final<<<nb, SCAN_T, 0, stream>>>(cnt, bsum, rowptr, n);
    scatter_kernel<<<eb, 256, 0, stream>>>(row, col, ew, dis, rowptr, rank, ecn, e);

    const int pb = (n + 3) / 4;   // one wave per row, 4 waves/block

    // conv1: T1 = prop(XH) -> U (+T1H); T2 = 2*prop(T1H) - x -> H; h = relu(dense) in U (+BN)
    prop_kernel<0,  true ><<<pb, 256, 0, stream>>>(XH,  x, rowptr, cnt, ecn, U, T1H, n);
    prop_kernel<NF, false><<<pb, 256, 0, stream>>>(T1H, x, rowptr, cnt, ecn, H, T1H, n);
    dense1_kernel<<<1024, 512, 0, stream>>>(x, U, H, W1, b1, stats, n);
    bn_finalize_kernel<<<1, 64, 0, stream>>>(stats, gamma, beta, 1.f / (float)n);
    bn_apply_kernel<<<2048, 256, 0, stream>>>(U, (__half2*)HH, stats, n * C1 / 4);

    // conv2: Q1 = prop(HH) -> H (+Q1H); T2' = 2*prop(Q1H) - hb -> S (+SH); out = MFMA dense
    prop_kernel<0,  true ><<<pb, 256, 0, stream>>>(HH,  U, rowptr, cnt, ecn, H, Q1H, n);
    prop_kernel<C1, true ><<<pb, 256, 0, stream>>>(Q1H, U, rowptr, cnt, ecn, S, SH, n);
    dense2_kernel<<<512, 512, 0, stream>>>(HH, Q1H, SH, WTh, b2, linW, linb, out, n);
}

// Round 22
// 440.867 us; speedup vs baseline: 1.1913x; 1.0791x over previous
//
#include <hip/hip_runtime.h>
#include <hip/hip_bf16.h>
#include <hip/hip_fp16.h>

static constexpr int NF   = 50;   // input features
static constexpr int C1   = 64;   // conv1/conv2 channels
static constexpr int OUTF = 16;   // final output features
static constexpr int SCAN_T = 256;
static constexpr int SCAN_I = 4;
static constexpr float DEG_SCALE   = 8388608.f;      // 2^23 fixed-point for packed deg
static constexpr float DEG_INV     = 1.f / 8388608.f;

typedef _Float16 half8 __attribute__((ext_vector_type(8)));
typedef float    f32x4 __attribute__((ext_vector_type(4)));

// ---------------------------------------------------------------- CSR build
__global__ void pass1_kernel(const int* __restrict__ row, const float* __restrict__ w,
                             unsigned long long* __restrict__ pcd, int* __restrict__ rank, int e)
{
    int i = blockIdx.x * blockDim.x + threadIdx.x;
    if (i < e) {
        int r = row[i];
        unsigned int wq = (unsigned int)(w[i] * DEG_SCALE + 0.5f);
        unsigned long long pk = (1ULL << 32) | (unsigned long long)wq;
        unsigned long long old = atomicAdd(&pcd[r], pk);
        rank[i] = (int)(old >> 32);
    }
}

__global__ void dis_kernel(const unsigned long long* __restrict__ pcd,
                           float* __restrict__ dis, int* __restrict__ cnt, int n)
{
    int i = blockIdx.x * blockDim.x + threadIdx.x;
    if (i < n) {
        unsigned long long pk = pcd[i];
        int c = (int)(pk >> 32);
        float d = (float)(unsigned int)(pk & 0xFFFFFFFFu) * DEG_INV;
        cnt[i] = c;
        dis[i] = (d > 0.f) ? (1.f / sqrtf(d)) : 0.f;
    }
}

__global__ void scan_partial(const int* __restrict__ cnt, int* __restrict__ bsum, int n)
{
    __shared__ int sm[SCAN_T];
    int t = threadIdx.x;
    int base = blockIdx.x * SCAN_T * SCAN_I + t * SCAN_I;
    int s = 0;
    #pragma unroll
    for (int k = 0; k < SCAN_I; ++k) { int i = base + k; if (i < n) s += cnt[i]; }
    sm[t] = s; __syncthreads();
    for (int off = SCAN_T / 2; off > 0; off >>= 1) {
        if (t < off) sm[t] += sm[t + off];
        __syncthreads();
    }
    if (t == 0) bsum[blockIdx.x] = sm[0];
}

// single block; requires nb <= 256 (here nb = 98)
__global__ void scan_bsums(int* __restrict__ bsum, int nb)
{
    __shared__ int sm[256];
    int t = threadIdx.x;
    sm[t] = (t < nb) ? bsum[t] : 0;
    __syncthreads();
    for (int off = 1; off < 256; off <<= 1) {
        int v = (t >= off) ? sm[t - off] : 0;
        __syncthreads();
        sm[t] += v;
        __syncthreads();
    }
    if (t < nb) bsum[t] = (t == 0) ? 0 : sm[t - 1];   // exclusive
}

__global__ void scan_final(const int* __restrict__ cnt, const int* __restrict__ bsum,
                           int* __restrict__ rowptr, int n)
{
    __shared__ int sm[SCAN_T];
    int t = threadIdx.x;
    int base = blockIdx.x * SCAN_T * SCAN_I + t * SCAN_I;
    int v[SCAN_I]; int s = 0;
    #pragma unroll
    for (int k = 0; k < SCAN_I; ++k) { int i = base + k; v[k] = (i < n) ? cnt[i] : 0; s += v[k]; }
    sm[t] = s; __syncthreads();
    for (int off = 1; off < SCAN_T; off <<= 1) {
        int x = (t >= off) ? sm[t - off] : 0;
        __syncthreads();
        sm[t] += x;
        __syncthreads();
    }
    int pref = bsum[blockIdx.x] + sm[t] - s;   // thread-exclusive prefix
    #pragma unroll
    for (int k = 0; k < SCAN_I; ++k) {
        int i = base + k;
        if (i < n) { rowptr[i] = pref; pref += v[k]; }
    }
}

// atomic-free scatter: pos = rowptr[row] + rank. Writes interleaved (col, norm) int2.
__global__ void scatter_kernel(const int* __restrict__ row, const int* __restrict__ col,
                               const float* __restrict__ w, const float* __restrict__ dis,
                               const int* __restrict__ rowptr, const int* __restrict__ rank,
                               int2* __restrict__ ecn, int e)
{
    int i = blockIdx.x * blockDim.x + threadIdx.x;
    if (i < e) {
        int r = row[i], c = col[i];
        int pos = rowptr[r] + rank[i];
        float nv = -dis[r] * w[i] * dis[c];
        ecn[pos] = make_int2(c, __float_as_int(nv));
    }
}

// pad x [n][50] -> XH [n][64] fp16 (zeros beyond 50): gather tables are half the bytes
__global__ void padx_kernel(const float* __restrict__ x, __half* __restrict__ XH, int n64)
{
    int i = blockIdx.x * blockDim.x + threadIdx.x;
    if (i < n64) {
        int row = i >> 6, f = i & 63;
        XH[i] = __float2half((f < NF) ? x[row * NF + f] : 0.f);
    }
}

// transpose W2 [tap][k][col] fp32 -> WTh [tap][col][k] fp16 (MFMA B-frag contiguity)
__global__ void wprep_kernel(const float* __restrict__ W2, __half* __restrict__ WTh)
{
    int i = blockIdx.x * blockDim.x + threadIdx.x;
    if (i < 3 * C1 * C1) {
        int tap = i / (C1 * C1), rem = i % (C1 * C1), col = rem / C1, k = rem % C1;
        WTh[i] = __float2half(W2[tap * C1 * C1 + k * C1 + col]);
    }
}

// transpose W1 [tap][k=50][col] fp32 -> WTh1 [tap][col][k=64] fp16, zero-pad k>=50
__global__ void wprep1_kernel(const float* __restrict__ W1, __half* __restrict__ WTh1)
{
    int i = blockIdx.x * blockDim.x + threadIdx.x;
    if (i < 3 * C1 * C1) {
        int tap = i / (C1 * C1), rem = i % (C1 * C1), col = rem / C1, k = rem % C1;
        WTh1[i] = __float2half((k < NF) ? W1[(tap * NF + k) * C1 + col] : 0.f);
    }
}

// ---------------------------------------------------------------- propagate (pure gather)
// One wave per row, lane = feature, ZERO LDS, fp16 gather tables; masked unroll-8
// (measured-best R14). BS: base stride for fused T2 = 2*acc - base (0 = off).
template<int BS, bool SHADOW>
__global__ __launch_bounds__(256) void prop_kernel(
    const __half* __restrict__ xin, const float* __restrict__ base,
    const int* __restrict__ rowptr, const int* __restrict__ cnt,
    const int2* __restrict__ ecn, float* __restrict__ yout,
    __half* __restrict__ ysh, int n)
{
    int gw = (blockIdx.x * blockDim.x + threadIdx.x) >> 6;
    int lane = threadIdx.x & 63;
    if (gw >= n) return;
    int st = __builtin_amdgcn_readfirstlane(rowptr[gw]);
    int m  = __builtin_amdgcn_readfirstlane(cnt[gw]);
    float a[8] = {0.f, 0.f, 0.f, 0.f, 0.f, 0.f, 0.f, 0.f};
    for (int t = 0; t < m; t += 8) {
        #pragma unroll
        for (int k = 0; k < 8; ++k) {
            int tk = t + k;
            int idx = st + min(tk, m - 1);             // clamped: valid when m>=1
            int2 md = ecn[idx];
            float nv = (tk < m) ? __int_as_float(md.y) : 0.f;
            a[k] += nv * __half2float(xin[md.x * C1 + lane]);
        }
    }
    float acc = ((a[0] + a[1]) + (a[2] + a[3])) + ((a[4] + a[5]) + (a[6] + a[7]));
    if (BS > 0) {   // T2 = 2*prop - base  (m==0: -base, correct)
        float bv = (BS == C1 || lane < BS) ? base[(size_t)gw * BS + lane] : 0.f;
        acc = 2.f * acc - bv;
    }
    yout[(size_t)gw * C1 + lane] = acc;
    if (SHADOW) ysh[(size_t)gw * C1 + lane] = __float2half(acc);
}

// ---------------------------------------------------------------- dense conv1 MFMA (+BN stats)
// h = relu(x@W0 + T1@W1 + T2@W2 + b1) -> U (fp32, pre-BN); BN partial sums per column.
// Same validated MFMA pattern as dense2 (R21): 16 rows/wave-tile, fp16 inputs,
// A-frag lane(row=l&15, k=(l>>4)*8); C/D col=lane&15, row=(lane>>4)*4+reg.
__global__ __launch_bounds__(512) void dense1_kernel(
    const __half* __restrict__ xh, const __half* __restrict__ t1h,
    const __half* __restrict__ t2h, const __half* __restrict__ WTh1,
    const float* __restrict__ b1, float* __restrict__ U,
    float* __restrict__ stats, int n)
{
    __shared__ float gst[8][16][65];          // 33.3 KB, pad 65: <=2-way (free)
    __shared__ float red[2][8][64];           // 4 KB
    const int tid = threadIdx.x;
    const int lane = tid & 63, wv = tid >> 6;
    const int cl = lane & 15, rg = lane >> 4;
    const int nt = n >> 4;                    // n % 16 == 0
    float ssum[4] = {0.f, 0.f, 0.f, 0.f}, ssq[4] = {0.f, 0.f, 0.f, 0.f};

    for (int tile = blockIdx.x * 8 + wv; tile < nt; tile += gridDim.x * 8) {
        int r0 = tile * 16;
        const __half* ta = xh  + (size_t)(r0 + cl) * C1 + rg * 8;
        const __half* tb = t1h + (size_t)(r0 + cl) * C1 + rg * 8;
        const __half* tc = t2h + (size_t)(r0 + cl) * C1 + rg * 8;
        half8 a00 = *(const half8*)(ta);   half8 a01 = *(const half8*)(ta + 32);
        half8 a10 = *(const half8*)(tb);   half8 a11 = *(const half8*)(tb + 32);
        half8 a20 = *(const half8*)(tc);   half8 a21 = *(const half8*)(tc + 32);

        #pragma unroll
        for (int ct = 0; ct < 4; ++ct) {
            float bias = b1[ct * 16 + cl];
            f32x4 acc = {bias, bias, bias, bias};
            const __half* wb = WTh1 + (ct * 16 + cl) * C1 + rg * 8;
            acc = __builtin_amdgcn_mfma_f32_16x16x32_f16(a00, *(const half8*)(wb),             acc, 0, 0, 0);
            acc = __builtin_amdgcn_mfma_f32_16x16x32_f16(a01, *(const half8*)(wb + 32),        acc, 0, 0, 0);
            acc = __builtin_amdgcn_mfma_f32_16x16x32_f16(a10, *(const half8*)(wb + 4096),      acc, 0, 0, 0);
            acc = __builtin_amdgcn_mfma_f32_16x16x32_f16(a11, *(const half8*)(wb + 4096 + 32), acc, 0, 0, 0);
            acc = __builtin_amdgcn_mfma_f32_16x16x32_f16(a20, *(const half8*)(wb + 8192),      acc, 0, 0, 0);
            acc = __builtin_amdgcn_mfma_f32_16x16x32_f16(a21, *(const half8*)(wb + 8192 + 32), acc, 0, 0, 0);
            #pragma unroll
            for (int r = 0; r < 4; ++r) {
                float v = fmaxf(acc[r], 0.f);
                gst[wv][rg * 4 + r][ct * 16 + cl] = v;
                ssum[ct] += v; ssq[ct] += v * v;
            }
        }
        // same-wave DS in-order; coalesced fp32 h write (BN applies in place later)
        #pragma unroll
        for (int row = 0; row < 16; ++row)
            U[(size_t)(r0 + row) * C1 + lane] = gst[wv][row][lane];
    }
    // reduce BN partials over the 4 rg lanes sharing each column
    #pragma unroll
    for (int ct = 0; ct < 4; ++ct) {
        ssum[ct] += __shfl_xor(ssum[ct], 16); ssum[ct] += __shfl_xor(ssum[ct], 32);
        ssq[ct]  += __shfl_xor(ssq[ct], 16);  ssq[ct]  += __shfl_xor(ssq[ct], 32);
    }
    if (rg == 0) {
        #pragma unroll
        for (int ct = 0; ct < 4; ++ct) {
            red[0][wv][ct * 16 + cl] = ssum[ct];
            red[1][wv][ct * 16 + cl] = ssq[ct];
        }
    }
    __syncthreads();
    if (tid < 128) {
        int which = tid >> 6, j = tid & 63;
        float tot = 0.f;
        #pragma unroll
        for (int wq = 0; wq < 8; ++wq) tot += red[which][wq][j];
        atomicAdd(&stats[which * 64 + j], tot);
    }
}

// ---------------------------------------------------------------- batch norm
__global__ void bn_finalize_kernel(float* __restrict__ stats, const float* __restrict__ gamma,
                                   const float* __restrict__ beta, float inv_n)
{
    int j = threadIdx.x;
    if (j < 64) {
        float mu   = stats[j] * inv_n;
        float var  = stats[64 + j] * inv_n - mu * mu;
        float rstd = 1.f / sqrtf(var + 1e-5f);
        float sc   = gamma[j] * rstd;
        stats[128 + j] = sc;
        stats[192 + j] = beta[j] - mu * sc;
    }
}

// BN in-place on fp32 h; also emits the fp16 shadow HH for conv2's gathers + MFMA.
__global__ void bn_apply_kernel(float* __restrict__ h, __half2* __restrict__ hh,
                                const float* __restrict__ stats, int n4)
{
    int i = blockIdx.x * blockDim.x + threadIdx.x;
    const int stride = gridDim.x * blockDim.x;      // multiple of 16 -> j0 invariant
    int j0 = (i * 4) & 63;
    float s0 = stats[128 + j0], s1 = stats[129 + j0], s2 = stats[130 + j0], s3 = stats[131 + j0];
    float b0 = stats[192 + j0], b1 = stats[193 + j0], b2 = stats[194 + j0], b3 = stats[195 + j0];
    float4* h4 = (float4*)h;
    for (; i < n4; i += stride) {
        float4 v = h4[i];
        v.x = v.x * s0 + b0;
        v.y = v.y * s1 + b1;
        v.z = v.z * s2 + b2;
        v.w = v.w * s3 + b3;
        h4[i] = v;
        hh[i * 2 + 0] = __floats2half2_rn(v.x, v.y);
        hh[i * 2 + 1] = __floats2half2_rn(v.z, v.w);
    }
}

// ---------------------------------------------------------------- dense conv2 + final linear (MFMA)
// Validated R21 kernel: g = relu(hb@W0 + Q1@W1 + T2'@W2 + b2); out = g @ linW^T + linb
__global__ __launch_bounds__(512) void dense2_kernel(
    const __half* __restrict__ hb16, const __half* __restrict__ q16,
    const __half* __restrict__ t16,  const __half* __restrict__ WTh,
    const float* __restrict__ b2, const float* __restrict__ linW,
    const float* __restrict__ linb, float* __restrict__ out, int n)
{
    __shared__ float LWT[C1 * OUTF];          // [j][o], 4 KB
    __shared__ float gst[8][16][65];          // 33.3 KB
    const int tid = threadIdx.x;
    for (int i = tid; i < C1 * OUTF; i += 512) {
        int j = i / OUTF, o = i % OUTF;
        LWT[i] = linW[o * C1 + j];
    }
    __syncthreads();

    const int lane = tid & 63, wv = tid >> 6;
    const int cl = lane & 15, rg = lane >> 4;
    const int nt = n >> 4;
    const float lb = linb[cl];

    for (int tile = blockIdx.x * 8 + wv; tile < nt; tile += gridDim.x * 8) {
        int r0 = tile * 16;
        const __half* ta = hb16 + (size_t)(r0 + cl) * C1 + rg * 8;
        const __half* tb = q16  + (size_t)(r0 + cl) * C1 + rg * 8;
        const __half* tc = t16  + (size_t)(r0 + cl) * C1 + rg * 8;
        half8 a00 = *(const half8*)(ta);   half8 a01 = *(const half8*)(ta + 32);
        half8 a10 = *(const half8*)(tb);   half8 a11 = *(const half8*)(tb + 32);
        half8 a20 = *(const half8*)(tc);   half8 a21 = *(const half8*)(tc + 32);

        #pragma unroll
        for (int ct = 0; ct < 4; ++ct) {
            float bias = b2[ct * 16 + cl];
            f32x4 acc = {bias, bias, bias, bias};
            const __half* wb = WTh + (ct * 16 + cl) * C1 + rg * 8;
            acc = __builtin_amdgcn_mfma_f32_16x16x32_f16(a00, *(const half8*)(wb),              acc, 0, 0, 0);
            acc = __builtin_amdgcn_mfma_f32_16x16x32_f16(a01, *(const half8*)(wb + 32),         acc, 0, 0, 0);
            acc = __builtin_amdgcn_mfma_f32_16x16x32_f16(a10, *(const half8*)(wb + 4096),       acc, 0, 0, 0);
            acc = __builtin_amdgcn_mfma_f32_16x16x32_f16(a11, *(const half8*)(wb + 4096 + 32),  acc, 0, 0, 0);
            acc = __builtin_amdgcn_mfma_f32_16x16x32_f16(a20, *(const half8*)(wb + 8192),       acc, 0, 0, 0);
            acc = __builtin_amdgcn_mfma_f32_16x16x32_f16(a21, *(const half8*)(wb + 8192 + 32),  acc, 0, 0, 0);
            #pragma unroll
            for (int r = 0; r < 4; ++r)
                gst[wv][rg * 4 + r][ct * 16 + cl] = fmaxf(acc[r], 0.f);
        }
        #pragma unroll
        for (int r4 = 0; r4 < 4; ++r4) {
            int row = r4 * 4 + rg;
            float oa = lb;
            #pragma unroll 8
            for (int j = 0; j < C1; ++j)
                oa += gst[wv][row][j] * LWT[j * OUTF + cl];
            out[(size_t)(r0 + row) * OUTF + cl] = oa;
        }
    }
}

// ---------------------------------------------------------------- launch
extern "C" void kernel_launch(void* const* d_in, const int* in_sizes, int n_in,
                              void* d_out, int out_size, void* d_ws, size_t ws_size,
                              hipStream_t stream)
{
    const float* x     = (const float*)d_in[0];
    const int*   ei    = (const int*)  d_in[1];
    const float* ew    = (const float*)d_in[2];
    const float* W1    = (const float*)d_in[3];
    const float* b1    = (const float*)d_in[4];
    const float* W2    = (const float*)d_in[5];
    const float* b2    = (const float*)d_in[6];
    const float* gamma = (const float*)d_in[7];
    const float* beta  = (const float*)d_in[8];
    const float* linW  = (const float*)d_in[9];
    const float* linb  = (const float*)d_in[10];
    float* out = (float*)d_out;
    (void)n_in; (void)out_size; (void)ws_size;

    const int n = in_sizes[0] / NF;    // 100000
    const int e = in_sizes[2];         // 1600000
    const int* row = ei;
    const int* col = ei + e;

    char* ws = (char*)d_ws;
    size_t off = 0;
    auto alloc = [&](size_t bytes) -> void* {
        void* p = ws + off;
        off += (bytes + 255) & ~(size_t)255;
        return p;
    };
    unsigned long long* pcd = (unsigned long long*)alloc((size_t)n * 8);
    float*  dis    = (float*)alloc((size_t)n * 4);
    int*    cnt    = (int*)  alloc((size_t)n * 4);
    int*    rowptr = (int*)  alloc((size_t)n * 4);
    int*    rank   = (int*)  alloc((size_t)e * 4);
    int*    bsum   = (int*)  alloc(256 * 4);
    float*  stats  = (float*)alloc(256 * 4);        // [sum|sumsq|scale|shift] x 64
    int2*   ecn    = (int2*) alloc((size_t)e * 8);  // interleaved (col, norm)
    __half* XH     = (__half*)alloc((size_t)n * C1 * 2);   // fp16 padded x
    __half* T1H    = (__half*)alloc((size_t)n * C1 * 2);   // fp16 shadow of T1
    __half* T2H    = (__half*)alloc((size_t)n * C1 * 2);   // fp16 shadow of T2
    __half* HH     = (__half*)alloc((size_t)n * C1 * 2);   // fp16 shadow of hb
    __half* Q1H    = (__half*)alloc((size_t)n * C1 * 2);   // fp16 shadow of Q1
    __half* SH     = (__half*)alloc((size_t)n * C1 * 2);   // fp16 shadow of T2'
    __half* WTh    = (__half*)alloc((size_t)3 * C1 * C1 * 2); // fp16 W2 transposed
    __half* WTh1   = (__half*)alloc((size_t)3 * C1 * C1 * 2); // fp16 W1 transposed+padded
    float*  U      = (float*)alloc((size_t)n * C1 * 4);    // T1, then h/hb (in-place)
    float*  H      = (float*)alloc((size_t)n * C1 * 4);    // T2, then Q1
    float*  S      = (float*)alloc((size_t)n * C1 * 4);    // T2' (conv2)

    hipMemsetAsync(pcd,   0, (size_t)n * 8, stream);
    hipMemsetAsync(stats, 0, 256 * 4, stream);

    const int eb  = (e + 255) / 256;
    const int nbk = (n + 255) / 256;
    pass1_kernel<<<eb, 256, 0, stream>>>(row, ew, pcd, rank, e);
    dis_kernel<<<nbk, 256, 0, stream>>>(pcd, dis, cnt, n);
    padx_kernel<<<(n * C1 + 255) / 256, 256, 0, stream>>>(x, XH, n * C1);
    wprep_kernel<<<(3 * C1 * C1 + 255) / 256, 256, 0, stream>>>(W2, WTh);
    wprep1_kernel<<<(3 * C1 * C1 + 255) / 256, 256, 0, stream>>>(W1, WTh1);

    const int nb = (n + SCAN_T * SCAN_I - 1) / (SCAN_T * SCAN_I);   // 98 <= 256
    scan_partial<<<nb, SCAN_T, 0, stream>>>(cnt, bsum, n);
    scan_bsums<<<1, 256, 0, stream>>>(bsum, nb);
    scan_final<<<nb, SCAN_T, 0, stream>>>(cnt, bsum, rowptr, n);
    scatter_kernel<<<eb, 256, 0, stream>>>(row, col, ew, dis, rowptr, rank, ecn, e);

    const int pb = (n + 3) / 4;   // one wave per row, 4 waves/block

    // conv1: T1 = prop(XH) -> U (+T1H); T2 = 2*prop(T1H) - x -> H (+T2H);
    //        h = relu(MFMA dense) -> U (+BN stats)
    prop_kernel<0,  true ><<<pb, 256, 0, stream>>>(XH,  x, rowptr, cnt, ecn, U, T1H, n);
    prop_kernel<NF, true ><<<pb, 256, 0, stream>>>(T1H, x, rowptr, cnt, ecn, H, T2H, n);
    dense1_kernel<<<512, 512, 0, stream>>>(XH, T1H, T2H, WTh1, b1, U, stats, n);
    bn_finalize_kernel<<<1, 64, 0, stream>>>(stats, gamma, beta, 1.f / (float)n);
    bn_apply_kernel<<<2048, 256, 0, stream>>>(U, (__half2*)HH, stats, n * C1 / 4);

    // conv2: Q1 = prop(HH) -> H (+Q1H); T2' = 2*prop(Q1H) - hb -> S (+SH); out = MFMA dense
    prop_kernel<0,  true ><<<pb, 256, 0, stream>>>(HH,  U, rowptr, cnt, ecn, H, Q1H, n);
    prop_kernel<C1, true ><<<pb, 256, 0, stream>>>(Q1H, U, rowptr, cnt, ecn, S, SH, n);
    dense2_kernel<<<512, 512, 0, stream>>>(HH, Q1H, SH, WTh, b2, linW, linb, out, n);
}

// Round 23
// 429.881 us; speedup vs baseline: 1.2218x; 1.0256x over previous
//
#include <hip/hip_runtime.h>
#include <hip/hip_bf16.h>
#include <hip/hip_fp16.h>

static constexpr int NF   = 50;   // input features
static constexpr int C1   = 64;   // conv1/conv2 channels
static constexpr int OUTF = 16;   // final output features
static constexpr int SCAN_T = 256;
static constexpr int SCAN_I = 4;
static constexpr float DEG_SCALE   = 8388608.f;      // 2^23 fixed-point for packed deg
static constexpr float DEG_INV     = 1.f / 8388608.f;

typedef _Float16 half8 __attribute__((ext_vector_type(8)));
typedef float    f32x4 __attribute__((ext_vector_type(4)));

// ---------------------------------------------------------------- CSR build
__global__ void pass1_kernel(const int* __restrict__ row, const float* __restrict__ w,
                             unsigned long long* __restrict__ pcd, int* __restrict__ rank, int e)
{
    int i = blockIdx.x * blockDim.x + threadIdx.x;
    if (i < e) {
        int r = row[i];
        unsigned int wq = (unsigned int)(w[i] * DEG_SCALE + 0.5f);
        unsigned long long pk = (1ULL << 32) | (unsigned long long)wq;
        unsigned long long old = atomicAdd(&pcd[r], pk);
        rank[i] = (int)(old >> 32);
    }
}

__global__ void dis_kernel(const unsigned long long* __restrict__ pcd,
                           float* __restrict__ dis, int* __restrict__ cnt, int n)
{
    int i = blockIdx.x * blockDim.x + threadIdx.x;
    if (i < n) {
        unsigned long long pk = pcd[i];
        int c = (int)(pk >> 32);
        float d = (float)(unsigned int)(pk & 0xFFFFFFFFu) * DEG_INV;
        cnt[i] = c;
        dis[i] = (d > 0.f) ? (1.f / sqrtf(d)) : 0.f;
    }
}

__global__ void scan_partial(const int* __restrict__ cnt, int* __restrict__ bsum, int n)
{
    __shared__ int sm[SCAN_T];
    int t = threadIdx.x;
    int base = blockIdx.x * SCAN_T * SCAN_I + t * SCAN_I;
    int s = 0;
    #pragma unroll
    for (int k = 0; k < SCAN_I; ++k) { int i = base + k; if (i < n) s += cnt[i]; }
    sm[t] = s; __syncthreads();
    for (int off = SCAN_T / 2; off > 0; off >>= 1) {
        if (t < off) sm[t] += sm[t + off];
        __syncthreads();
    }
    if (t == 0) bsum[blockIdx.x] = sm[0];
}

// single block; requires nb <= 256 (here nb = 98)
__global__ void scan_bsums(int* __restrict__ bsum, int nb)
{
    __shared__ int sm[256];
    int t = threadIdx.x;
    sm[t] = (t < nb) ? bsum[t] : 0;
    __syncthreads();
    for (int off = 1; off < 256; off <<= 1) {
        int v = (t >= off) ? sm[t - off] : 0;
        __syncthreads();
        sm[t] += v;
        __syncthreads();
    }
    if (t < nb) bsum[t] = (t == 0) ? 0 : sm[t - 1];   // exclusive
}

__global__ void scan_final(const int* __restrict__ cnt, const int* __restrict__ bsum,
                           int* __restrict__ rowptr, int n)
{
    __shared__ int sm[SCAN_T];
    int t = threadIdx.x;
    int base = blockIdx.x * SCAN_T * SCAN_I + t * SCAN_I;
    int v[SCAN_I]; int s = 0;
    #pragma unroll
    for (int k = 0; k < SCAN_I; ++k) { int i = base + k; v[k] = (i < n) ? cnt[i] : 0; s += v[k]; }
    sm[t] = s; __syncthreads();
    for (int off = 1; off < SCAN_T; off <<= 1) {
        int x = (t >= off) ? sm[t - off] : 0;
        __syncthreads();
        sm[t] += x;
        __syncthreads();
    }
    int pref = bsum[blockIdx.x] + sm[t] - s;   // thread-exclusive prefix
    #pragma unroll
    for (int k = 0; k < SCAN_I; ++k) {
        int i = base + k;
        if (i < n) { rowptr[i] = pref; pref += v[k]; }
    }
}

// atomic-free scatter: pos = rowptr[row] + rank. Writes interleaved (col, norm) int2.
__global__ void scatter_kernel(const int* __restrict__ row, const int* __restrict__ col,
                               const float* __restrict__ w, const float* __restrict__ dis,
                               const int* __restrict__ rowptr, const int* __restrict__ rank,
                               int2* __restrict__ ecn, int e)
{
    int i = blockIdx.x * blockDim.x + threadIdx.x;
    if (i < e) {
        int r = row[i], c = col[i];
        int pos = rowptr[r] + rank[i];
        float nv = -dis[r] * w[i] * dis[c];
        ecn[pos] = make_int2(c, __float_as_int(nv));
    }
}

// pad x [n][50] -> XH [n][64] fp16 (zeros beyond 50): gather tables are half the bytes
__global__ void padx_kernel(const float* __restrict__ x, __half* __restrict__ XH, int n64)
{
    int i = blockIdx.x * blockDim.x + threadIdx.x;
    if (i < n64) {
        int row = i >> 6, f = i & 63;
        XH[i] = __float2half((f < NF) ? x[row * NF + f] : 0.f);
    }
}

// transpose W2 [tap][k][col] fp32 -> WTh [tap][col][k] fp16 (MFMA B-frag contiguity)
__global__ void wprep_kernel(const float* __restrict__ W2, __half* __restrict__ WTh)
{
    int i = blockIdx.x * blockDim.x + threadIdx.x;
    if (i < 3 * C1 * C1) {
        int tap = i / (C1 * C1), rem = i % (C1 * C1), col = rem / C1, k = rem % C1;
        WTh[i] = __float2half(W2[tap * C1 * C1 + k * C1 + col]);
    }
}

// transpose W1 [tap][k=50][col] fp32 -> WTh1 [tap][col][k=64] fp16, zero-pad k>=50
__global__ void wprep1_kernel(const float* __restrict__ W1, __half* __restrict__ WTh1)
{
    int i = blockIdx.x * blockDim.x + threadIdx.x;
    if (i < 3 * C1 * C1) {
        int tap = i / (C1 * C1), rem = i % (C1 * C1), col = rem / C1, k = rem % C1;
        WTh1[i] = __float2half((k < NF) ? W1[(tap * NF + k) * C1 + col] : 0.f);
    }
}

// ---------------------------------------------------------------- propagate (pure gather)
// One wave per row, lane = feature, ZERO LDS, fp16 in AND out (fp32 outputs were
// dead: all dense consumers read the fp16 shadows). Masked unroll-8 (R14-best).
// T2MODE: fuse T2 = 2*acc - base[row] with fp16 base (zero-padded -> no masking).
template<bool T2MODE>
__global__ __launch_bounds__(256) void prop_kernel(
    const __half* __restrict__ xin, const __half* __restrict__ base,
    const int* __restrict__ rowptr, const int* __restrict__ cnt,
    const int2* __restrict__ ecn, __half* __restrict__ ysh, int n)
{
    int gw = (blockIdx.x * blockDim.x + threadIdx.x) >> 6;
    int lane = threadIdx.x & 63;
    if (gw >= n) return;
    int st = __builtin_amdgcn_readfirstlane(rowptr[gw]);
    int m  = __builtin_amdgcn_readfirstlane(cnt[gw]);
    float a[8] = {0.f, 0.f, 0.f, 0.f, 0.f, 0.f, 0.f, 0.f};
    for (int t = 0; t < m; t += 8) {
        #pragma unroll
        for (int k = 0; k < 8; ++k) {
            int tk = t + k;
            int idx = st + min(tk, m - 1);             // clamped: valid when m>=1
            int2 md = ecn[idx];
            float nv = (tk < m) ? __int_as_float(md.y) : 0.f;
            a[k] += nv * __half2float(xin[md.x * C1 + lane]);
        }
    }
    float acc = ((a[0] + a[1]) + (a[2] + a[3])) + ((a[4] + a[5]) + (a[6] + a[7]));
    if (T2MODE)   // T2 = 2*prop - base  (m==0: -base, correct; pads are zero)
        acc = 2.f * acc - __half2float(base[(size_t)gw * C1 + lane]);
    ysh[(size_t)gw * C1 + lane] = __float2half(acc);
}

// ---------------------------------------------------------------- dense conv1 MFMA (+BN stats)
// h = relu(x@W0 + T1@W1 + T2@W2 + b1) -> HPRE (fp16, pre-BN); BN stats in fp32.
// Validated MFMA pattern (R21/R22): 16 rows/wave-tile, fp16 inputs,
// A-frag lane(row=l&15, k=(l>>4)*8); C/D col=lane&15, row=(lane>>4)*4+reg.
__global__ __launch_bounds__(512) void dense1_kernel(
    const __half* __restrict__ xh, const __half* __restrict__ t1h,
    const __half* __restrict__ t2h, const __half* __restrict__ WTh1,
    const float* __restrict__ b1, __half* __restrict__ HPRE,
    float* __restrict__ stats, int n)
{
    __shared__ float gst[8][16][65];          // 33.3 KB, pad 65: <=2-way (free)
    __shared__ float red[2][8][64];           // 4 KB
    const int tid = threadIdx.x;
    const int lane = tid & 63, wv = tid >> 6;
    const int cl = lane & 15, rg = lane >> 4;
    const int nt = n >> 4;                    // n % 16 == 0
    float ssum[4] = {0.f, 0.f, 0.f, 0.f}, ssq[4] = {0.f, 0.f, 0.f, 0.f};

    for (int tile = blockIdx.x * 8 + wv; tile < nt; tile += gridDim.x * 8) {
        int r0 = tile * 16;
        const __half* ta = xh  + (size_t)(r0 + cl) * C1 + rg * 8;
        const __half* tb = t1h + (size_t)(r0 + cl) * C1 + rg * 8;
        const __half* tc = t2h + (size_t)(r0 + cl) * C1 + rg * 8;
        half8 a00 = *(const half8*)(ta);   half8 a01 = *(const half8*)(ta + 32);
        half8 a10 = *(const half8*)(tb);   half8 a11 = *(const half8*)(tb + 32);
        half8 a20 = *(const half8*)(tc);   half8 a21 = *(const half8*)(tc + 32);

        #pragma unroll
        for (int ct = 0; ct < 4; ++ct) {
            float bias = b1[ct * 16 + cl];
            f32x4 acc = {bias, bias, bias, bias};
            const __half* wb = WTh1 + (ct * 16 + cl) * C1 + rg * 8;
            acc = __builtin_amdgcn_mfma_f32_16x16x32_f16(a00, *(const half8*)(wb),             acc, 0, 0, 0);
            acc = __builtin_amdgcn_mfma_f32_16x16x32_f16(a01, *(const half8*)(wb + 32),        acc, 0, 0, 0);
            acc = __builtin_amdgcn_mfma_f32_16x16x32_f16(a10, *(const half8*)(wb + 4096),      acc, 0, 0, 0);
            acc = __builtin_amdgcn_mfma_f32_16x16x32_f16(a11, *(const half8*)(wb + 4096 + 32), acc, 0, 0, 0);
            acc = __builtin_amdgcn_mfma_f32_16x16x32_f16(a20, *(const half8*)(wb + 8192),      acc, 0, 0, 0);
            acc = __builtin_amdgcn_mfma_f32_16x16x32_f16(a21, *(const half8*)(wb + 8192 + 32), acc, 0, 0, 0);
            #pragma unroll
            for (int r = 0; r < 4; ++r) {
                float v = fmaxf(acc[r], 0.f);
                gst[wv][rg * 4 + r][ct * 16 + cl] = v;
                ssum[ct] += v; ssq[ct] += v * v;
            }
        }
        // same-wave DS in-order; coalesced fp16 pre-BN h write (128B/row)
        #pragma unroll
        for (int row = 0; row < 16; ++row)
            HPRE[(size_t)(r0 + row) * C1 + lane] = __float2half(gst[wv][row][lane]);
    }
    // reduce BN partials over the 4 rg lanes sharing each column
    #pragma unroll
    for (int ct = 0; ct < 4; ++ct) {
        ssum[ct] += __shfl_xor(ssum[ct], 16); ssum[ct] += __shfl_xor(ssum[ct], 32);
        ssq[ct]  += __shfl_xor(ssq[ct], 16);  ssq[ct]  += __shfl_xor(ssq[ct], 32);
    }
    if (rg == 0) {
        #pragma unroll
        for (int ct = 0; ct < 4; ++ct) {
            red[0][wv][ct * 16 + cl] = ssum[ct];
            red[1][wv][ct * 16 + cl] = ssq[ct];
        }
    }
    __syncthreads();
    if (tid < 128) {
        int which = tid >> 6, j = tid & 63;
        float tot = 0.f;
        #pragma unroll
        for (int wq = 0; wq < 8; ++wq) tot += red[which][wq][j];
        atomicAdd(&stats[which * 64 + j], tot);
    }
}

// ---------------------------------------------------------------- batch norm
__global__ void bn_finalize_kernel(float* __restrict__ stats, const float* __restrict__ gamma,
                                   const float* __restrict__ beta, float inv_n)
{
    int j = threadIdx.x;
    if (j < 64) {
        float mu   = stats[j] * inv_n;
        float var  = stats[64 + j] * inv_n - mu * mu;
        float rstd = 1.f / sqrtf(var + 1e-5f);
        float sc   = gamma[j] * rstd;
        stats[128 + j] = sc;
        stats[192 + j] = beta[j] - mu * sc;
    }
}

// BN: read fp16 pre-BN h, apply fp32 scale/shift, write fp16 HH (conv2's only input).
// 8 halves (16B) per thread; stride multiple of 8 -> feature offset invariant.
__global__ void bn_apply_kernel(const __half* __restrict__ hpre, __half* __restrict__ hh,
                                const float* __restrict__ stats, int n8)
{
    int i = blockIdx.x * blockDim.x + threadIdx.x;
    const int stride = gridDim.x * blockDim.x;
    int j0 = (i * 8) & 63;
    float sc[8], sh[8];
    #pragma unroll
    for (int k = 0; k < 8; ++k) { sc[k] = stats[128 + j0 + k]; sh[k] = stats[192 + j0 + k]; }
    const uint4* hp4 = (const uint4*)hpre;
    uint4* hh4 = (uint4*)hh;
    for (; i < n8; i += stride) {
        uint4 v = hp4[i];
        const __half2* h2 = (const __half2*)&v;
        uint4 o;
        __half2* o2 = (__half2*)&o;
        #pragma unroll
        for (int k = 0; k < 4; ++k) {
            float2 f = __half22float2(h2[k]);
            o2[k] = __floats2half2_rn(f.x * sc[2 * k] + sh[2 * k],
                                      f.y * sc[2 * k + 1] + sh[2 * k + 1]);
        }
        hh4[i] = o;
    }
}

// ---------------------------------------------------------------- dense conv2 + final linear (MFMA)
// Validated R21 kernel: g = relu(hb@W0 + Q1@W1 + T2'@W2 + b2); out = g @ linW^T + linb
__global__ __launch_bounds__(512) void dense2_kernel(
    const __half* __restrict__ hb16, const __half* __restrict__ q16,
    const __half* __restrict__ t16,  const __half* __restrict__ WTh,
    const float* __restrict__ b2, const float* __restrict__ linW,
    const float* __restrict__ linb, float* __restrict__ out, int n)
{
    __shared__ float LWT[C1 * OUTF];          // [j][o], 4 KB
    __shared__ float gst[8][16][65];          // 33.3 KB
    const int tid = threadIdx.x;
    for (int i = tid; i < C1 * OUTF; i += 512) {
        int j = i / OUTF, o = i % OUTF;
        LWT[i] = linW[o * C1 + j];
    }
    __syncthreads();

    const int lane = tid & 63, wv = tid >> 6;
    const int cl = lane & 15, rg = lane >> 4;
    const int nt = n >> 4;
    const float lb = linb[cl];

    for (int tile = blockIdx.x * 8 + wv; tile < nt; tile += gridDim.x * 8) {
        int r0 = tile * 16;
        const __half* ta = hb16 + (size_t)(r0 + cl) * C1 + rg * 8;
        const __half* tb = q16  + (size_t)(r0 + cl) * C1 + rg * 8;
        const __half* tc = t16  + (size_t)(r0 + cl) * C1 + rg * 8;
        half8 a00 = *(const half8*)(ta);   half8 a01 = *(const half8*)(ta + 32);
        half8 a10 = *(const half8*)(tb);   half8 a11 = *(const half8*)(tb + 32);
        half8 a20 = *(const half8*)(tc);   half8 a21 = *(const half8*)(tc + 32);

        #pragma unroll
        for (int ct = 0; ct < 4; ++ct) {
            float bias = b2[ct * 16 + cl];
            f32x4 acc = {bias, bias, bias, bias};
            const __half* wb = WTh + (ct * 16 + cl) * C1 + rg * 8;
            acc = __builtin_amdgcn_mfma_f32_16x16x32_f16(a00, *(const half8*)(wb),              acc, 0, 0, 0);
            acc = __builtin_amdgcn_mfma_f32_16x16x32_f16(a01, *(const half8*)(wb + 32),         acc, 0, 0, 0);
            acc = __builtin_amdgcn_mfma_f32_16x16x32_f16(a10, *(const half8*)(wb + 4096),       acc, 0, 0, 0);
            acc = __builtin_amdgcn_mfma_f32_16x16x32_f16(a11, *(const half8*)(wb + 4096 + 32),  acc, 0, 0, 0);
            acc = __builtin_amdgcn_mfma_f32_16x16x32_f16(a20, *(const half8*)(wb + 8192),       acc, 0, 0, 0);
            acc = __builtin_amdgcn_mfma_f32_16x16x32_f16(a21, *(const half8*)(wb + 8192 + 32),  acc, 0, 0, 0);
            #pragma unroll
            for (int r = 0; r < 4; ++r)
                gst[wv][rg * 4 + r][ct * 16 + cl] = fmaxf(acc[r], 0.f);
        }
        #pragma unroll
        for (int r4 = 0; r4 < 4; ++r4) {
            int row = r4 * 4 + rg;
            float oa = lb;
            #pragma unroll 8
            for (int j = 0; j < C1; ++j)
                oa += gst[wv][row][j] * LWT[j * OUTF + cl];
            out[(size_t)(r0 + row) * OUTF + cl] = oa;
        }
    }
}

// ---------------------------------------------------------------- launch
extern "C" void kernel_launch(void* const* d_in, const int* in_sizes, int n_in,
                              void* d_out, int out_size, void* d_ws, size_t ws_size,
                              hipStream_t stream)
{
    const float* x     = (const float*)d_in[0];
    const int*   ei    = (const int*)  d_in[1];
    const float* ew    = (const float*)d_in[2];
    const float* W1    = (const float*)d_in[3];
    const float* b1    = (const float*)d_in[4];
    const float* W2    = (const float*)d_in[5];
    const float* b2    = (const float*)d_in[6];
    const float* gamma = (const float*)d_in[7];
    const float* beta  = (const float*)d_in[8];
    const float* linW  = (const float*)d_in[9];
    const float* linb  = (const float*)d_in[10];
    float* out = (float*)d_out;
    (void)n_in; (void)out_size; (void)ws_size;

    const int n = in_sizes[0] / NF;    // 100000
    const int e = in_sizes[2];         // 1600000
    const int* row = ei;
    const int* col = ei + e;

    char* ws = (char*)d_ws;
    size_t off = 0;
    auto alloc = [&](size_t bytes) -> void* {
        void* p = ws + off;
        off += (bytes + 255) & ~(size_t)255;
        return p;
    };
    unsigned long long* pcd = (unsigned long long*)alloc((size_t)n * 8);
    float*  dis    = (float*)alloc((size_t)n * 4);
    int*    cnt    = (int*)  alloc((size_t)n * 4);
    int*    rowptr = (int*)  alloc((size_t)n * 4);
    int*    rank   = (int*)  alloc((size_t)e * 4);
    int*    bsum   = (int*)  alloc(256 * 4);
    float*  stats  = (float*)alloc(256 * 4);        // [sum|sumsq|scale|shift] x 64
    int2*   ecn    = (int2*) alloc((size_t)e * 8);  // interleaved (col, norm)
    __half* XH     = (__half*)alloc((size_t)n * C1 * 2);   // fp16 padded x
    __half* T1H    = (__half*)alloc((size_t)n * C1 * 2);   // fp16 T1
    __half* T2H    = (__half*)alloc((size_t)n * C1 * 2);   // fp16 T2
    __half* HPRE   = (__half*)alloc((size_t)n * C1 * 2);   // fp16 pre-BN h
    __half* HH     = (__half*)alloc((size_t)n * C1 * 2);   // fp16 post-BN h
    __half* Q1H    = (__half*)alloc((size_t)n * C1 * 2);   // fp16 Q1
    __half* SH     = (__half*)alloc((size_t)n * C1 * 2);   // fp16 T2'
    __half* WTh    = (__half*)alloc((size_t)3 * C1 * C1 * 2); // fp16 W2 transposed
    __half* WTh1   = (__half*)alloc((size_t)3 * C1 * C1 * 2); // fp16 W1 transposed+padded

    hipMemsetAsync(pcd,   0, (size_t)n * 8, stream);
    hipMemsetAsync(stats, 0, 256 * 4, stream);

    const int eb  = (e + 255) / 256;
    const int nbk = (n + 255) / 256;
    pass1_kernel<<<eb, 256, 0, stream>>>(row, ew, pcd, rank, e);
    dis_kernel<<<nbk, 256, 0, stream>>>(pcd, dis, cnt, n);
    padx_kernel<<<(n * C1 + 255) / 256, 256, 0, stream>>>(x, XH, n * C1);
    wprep_kernel<<<(3 * C1 * C1 + 255) / 256, 256, 0, stream>>>(W2, WTh);
    wprep1_kernel<<<(3 * C1 * C1 + 255) / 256, 256, 0, stream>>>(W1, WTh1);

    const int nb = (n + SCAN_T * SCAN_I - 1) / (SCAN_T * SCAN_I);   // 98 <= 256
    scan_partial<<<nb, SCAN_T, 0, stream>>>(cnt, bsum, n);
    scan_bsums<<<1, 256, 0, stream>>>(bsum, nb);
    scan_final<<<nb, SCAN_T, 0, stream>>>(cnt, bsum, rowptr, n);
    scatter_kernel<<<eb, 256, 0, stream>>>(row, col, ew, dis, rowptr, rank, ecn, e);

    const int pb = (n + 3) / 4;   // one wave per row, 4 waves/block

    // conv1: T1H = prop(XH); T2H = 2*prop(T1H) - XH; HPRE = relu(MFMA dense) (+BN stats)
    prop_kernel<false><<<pb, 256, 0, stream>>>(XH,  XH, rowptr, cnt, ecn, T1H, n);
    prop_kernel<true ><<<pb, 256, 0, stream>>>(T1H, XH, rowptr, cnt, ecn, T2H, n);
    dense1_kernel<<<512, 512, 0, stream>>>(XH, T1H, T2H, WTh1, b1, HPRE, stats, n);
    bn_finalize_kernel<<<1, 64, 0, stream>>>(stats, gamma, beta, 1.f / (float)n);
    bn_apply_kernel<<<2048, 256, 0, stream>>>(HPRE, HH, stats, n * C1 / 8);

    // conv2: Q1H = prop(HH); SH = 2*prop(Q1H) - HH; out = MFMA dense + final linear
    prop_kernel<false><<<pb, 256, 0, stream>>>(HH,  HH, rowptr, cnt, ecn, Q1H, n);
    prop_kernel<true ><<<pb, 256, 0, stream>>>(Q1H, HH, rowptr, cnt, ecn, SH, n);
    dense2_kernel<<<512, 512, 0, stream>>>(HH, Q1H, SH, WTh, b2, linW, linb, out, n);
}